// Round 13
// baseline (6064.453 us; speedup 1.0000x reference)
//
#include <hip/hip_runtime.h>
#include <math.h>

#define BB 4
#define NN 2048
#define EE 16384
#define LL (EE + NN)      // 18432
#define ND_ 256
#define ED_ 128
#define TD_ 64
#define CC 512
#define HH 8
#define DH_ 64
#define C4 2048

typedef unsigned short u16;
typedef unsigned int u32;
typedef __bf16 bhalf8 __attribute__((ext_vector_type(8)));
typedef float f32x4 __attribute__((ext_vector_type(4)));

__device__ __forceinline__ u16 f2bf(float f) {
    union { float f; unsigned u; } c; c.f = f;
    const unsigned r = (c.u + 0x7fffu + ((c.u >> 16) & 1u)) >> 16;   // RNE
    return (u16)r;
}
__device__ __forceinline__ u16 f2bf_hw(float f) {      // native cvt (RNE)
    __bf16 h = (__bf16)f;
    union { __bf16 h; u16 u; } c; c.h = h; return c.u;
}
__device__ __forceinline__ float bf2f(u16 u) {
    union { unsigned u; float f; } c; c.u = ((unsigned)u) << 16; return c.f;
}
// tanh-form GELU: |err vs exact-erf gelu| ~3e-4, far below bf16 rounding
__device__ __forceinline__ float gelu_fast(float v) {
    const float u = v * (0.7978845608f + 0.0356774081f * v * v);
    const float e = __expf(2.0f * u);
    const float t = 1.0f - 2.0f / (e + 1.0f);
    return 0.5f * v * (1.0f + t);
}

#define GLD16(gp, lp) __builtin_amdgcn_global_load_lds( \
    (const __attribute__((address_space(1))) unsigned int*)(gp), \
    (__attribute__((address_space(3))) unsigned int*)(lp), 16, 0, 0)

// ---------------------------------------------------------------------------
// bf16 MFMA GEMM — BK=32, 64 KB LDS => 2 blocks/CU (4 waves/SIMD TLP):
//   Y[M x N](bf16) = A[M x K] @ W[N x K]^T + bias(f32)
// 256x256 block, 512 thr = 8 waves (2M x 4N), per-wave 128x64 output.
// Round-7 replay-proven skeleton: hoisted frag reads (12 b128/wave/tile),
// one 32-MFMA setprio cluster, stage tile t+2 after barrier, counted
// s_waitcnt vmcnt(4) (never 0 in steady state).
// Conflict-free BK=32 swizzle: row stride 64 B => bank-group g=(4r+s)%8;
// stored chunk s = c ^ ((r>>1)&3): 16 frag rows cover 8 groups 2-way (free,
// m136). Staging source chunk = (tid&3)^((tid>>3)&3), LDS dest linear
// (rule #21). M%256==0, N%256==0, K%64==0 (NT>=8 for all shapes here).
// ---------------------------------------------------------------------------
template<bool GELU>
__global__ __launch_bounds__(512, 4)
void gemm_mfma(const u16* __restrict__ A, const u16* __restrict__ W,
               const float* __restrict__ bias, u16* __restrict__ Y,
               int N, int K)
{
    __shared__ u16 As[2][8192];   // 256 rows x 32 bf16 per buffer (16 KB)
    __shared__ u16 Bs[2][8192];

    // bijective XCD-chunked swizzle (m204)
    const int o    = blockIdx.y * gridDim.x + blockIdx.x;
    const int nwg  = gridDim.x * gridDim.y;
    const int xcd  = o & 7;
    const int qq   = nwg >> 3, rr = nwg & 7;
    const int wg   = (xcd < rr ? xcd * (qq + 1) : rr * (qq + 1) + (xcd - rr) * qq) + (o >> 3);
    const int bx   = wg % gridDim.x;
    const int by   = wg / gridDim.x;
    const int m0   = by * 256;
    const int n0   = bx * 256;

    const int tid  = threadIdx.x;
    const int lane = tid & 63;
    const int wid  = tid >> 6;
    const int wm   = wid >> 2;          // wave row: 2 x 128 rows
    const int wn   = wid & 3;           // wave col: 4 x 64 cols

    // staging: thread t -> LDS row t>>2 (+128 for 2nd GLD), chunk t&3 (linear
    // dest). Inverse-swizzled global source chunk: (t&3) ^ ((t>>3)&3).
    const int csrc8 = (((tid & 3) ^ ((tid >> 3) & 3))) * 8;
    const size_t sK = (size_t)K;
    const u16* Agb = A + (size_t)(m0 + (tid >> 2)) * sK + csrc8;
    const u16* Wgb = W + (size_t)(n0 + (tid >> 2)) * sK + csrc8;

    const int NT  = K >> 5;             // K-tiles of 32
    const int rlo = lane & 15;
    const int hi4 = lane >> 4;          // frag chunk (k-slice) 0..3

#define STAGE(kt, buf) do {                                      \
    const u16* _ga = Agb + (size_t)(kt) * 32;                    \
    const u16* _gb = Wgb + (size_t)(kt) * 32;                    \
    u16* _la = &As[buf][tid * 8];                                \
    u16* _lb = &Bs[buf][tid * 8];                                \
    GLD16(_ga,            _la);                                  \
    GLD16(_ga + 128 * sK, _la + 4096);                           \
    GLD16(_gb,            _lb);                                  \
    GLD16(_gb + 128 * sK, _lb + 4096);                           \
} while (0)

// read: row R, k-slice hi4 -> stored chunk hi4 ^ ((R>>1)&3)
#define RDX(buf, R) (*(const bhalf8*)&(buf)[(R) * 32 + ((hi4 ^ (((R) >> 1) & 3)) << 3)])

    f32x4 acc[8][4] = {};

    // prologue: tiles 0 and 1 in flight; wait for tile 0 only (vmcnt(4))
    STAGE(0, 0);
    STAGE(1, 1);
    asm volatile("s_waitcnt vmcnt(4)" ::: "memory");
    __builtin_amdgcn_s_barrier();
    __builtin_amdgcn_sched_barrier(0);

    for (int t = 0; t < NT; ++t) {
        const u16* as = &As[t & 1][0];
        const u16* bs = &Bs[t & 1][0];

        bhalf8 a[8], b[4];
        #pragma unroll
        for (int i = 0; i < 8; ++i) {
            const int R = wm * 128 + i * 16 + rlo;
            a[i] = RDX(as, R);
        }
        #pragma unroll
        for (int j = 0; j < 4; ++j) {
            const int R = wn * 64 + j * 16 + rlo;
            b[j] = RDX(bs, R);
        }

        __builtin_amdgcn_s_setprio(1);
        #pragma unroll
        for (int i = 0; i < 8; ++i)
            #pragma unroll
            for (int j = 0; j < 4; ++j)   // swapped operands: row-major D
                acc[i][j] = __builtin_amdgcn_mfma_f32_16x16x32_bf16(b[j], a[i], acc[i][j], 0, 0, 0);
        __builtin_amdgcn_s_setprio(0);

        if (t == NT - 1) break;
        __builtin_amdgcn_sched_barrier(0);
        __builtin_amdgcn_s_barrier();            // all waves done reading buf[cur]
        __builtin_amdgcn_sched_barrier(0);
        if (t + 2 < NT) {
            STAGE(t + 2, t & 1);                 // refill just-freed buffer
            asm volatile("s_waitcnt vmcnt(4)" ::: "memory");   // t+1 landed; t+2 in flight
        } else {
            asm volatile("s_waitcnt vmcnt(0)" ::: "memory");   // drain t+1
        }
        __builtin_amdgcn_s_barrier();            // tile t+1 visible to all waves
        __builtin_amdgcn_sched_barrier(0);
    }
#undef STAGE
#undef RDX

    // Epilogue: row = m0+wm*128+i*16+(lane&15); cols = n0+wn*64+j*16+(lane>>4)*4
    const int row0 = m0 + wm * 128;
    const int col0 = n0 + wn * 64;
    const int rq   = (lane >> 4) * 4;
    float4 bi[4];
    #pragma unroll
    for (int j = 0; j < 4; ++j)
        bi[j] = *(const float4*)(bias + col0 + j * 16 + rq);

    #pragma unroll
    for (int i = 0; i < 8; ++i) {
        const int gr = row0 + i * 16 + rlo;
        u16* yrow = Y + (size_t)gr * N + col0;
        #pragma unroll
        for (int j = 0; j < 4; ++j) {
            float v0 = acc[i][j][0] + bi[j].x;
            float v1 = acc[i][j][1] + bi[j].y;
            float v2 = acc[i][j][2] + bi[j].z;
            float v3 = acc[i][j][3] + bi[j].w;
            if constexpr (GELU) {
                v0 = gelu_fast(v0); v1 = gelu_fast(v1);
                v2 = gelu_fast(v2); v3 = gelu_fast(v3);
            }
            ushort4 ov;
            ov.x = f2bf_hw(v0); ov.y = f2bf_hw(v1);
            ov.z = f2bf_hw(v2); ov.w = f2bf_hw(v3);
            *(ushort4*)(yrow + j * 16 + rq) = ov;
        }
    }
}

// ---------------------------------------------------------------------------
// Wbig builder: 2048x256 bf16.
// rows 0..511 = W_node[:,0:256]; 512..1023 = (Wq@W_node)[:,0:256];
// 1024..1535 = W_node[:,256:512]; 1536..2047 = (Wq@W_node)[:,256:512]
// ---------------------------------------------------------------------------
__global__ __launch_bounds__(256)
void build_wbig(const float* __restrict__ Wn, const float* __restrict__ Wq,
                u16* __restrict__ out)
{
    const int idx = blockIdx.x * 256 + threadIdx.x;   // 524288
    const int R = idx >> 8;
    const int k = idx & 255;
    float v;
    if (R < 512) {
        v = Wn[R * 512 + k];
    } else if (R < 1024) {
        const int c = R - 512; float a = 0.f;
        for (int j = 0; j < 512; j++) a += Wq[c * 512 + j] * Wn[j * 512 + k];
        v = a;
    } else if (R < 1536) {
        v = Wn[(R - 1024) * 512 + 256 + k];
    } else {
        const int c = R - 1536; float a = 0.f;
        for (int j = 0; j < 512; j++) a += Wq[c * 512 + j] * Wn[j * 512 + 256 + k];
        v = a;
    }
    out[idx] = f2bf(v);
}

// ---------------------------------------------------------------------------
// Wkt builder: 1024x256 bf16 (cols 128..255 zero padding), block-diag of
// wtk = Wk@W_timef: rows 0..511: [wtk[:,0:64] | 0...] ; 512..1023: [0 | wtk[:,64:128] | 0pad]
// ---------------------------------------------------------------------------
__global__ __launch_bounds__(256)
void build_wkt(const float* __restrict__ Wk, const float* __restrict__ Wtf,
               u16* __restrict__ out)
{
    const int idx = blockIdx.x * 256 + threadIdx.x;   // 262144
    const int R = idx >> 8;
    const int k = idx & 255;
    float v = 0.f;
    const bool live = (k < 128) && ((R < 512) ? (k < 64) : (k >= 64));
    if (live) {
        const int c = (R < 512) ? R : R - 512;
        float a = 0.f;
        for (int j = 0; j < 512; j++) a += Wk[c * 512 + j] * Wtf[j * 128 + k];
        v = a;
    }
    out[idx] = f2bf(v);
}

// ---------------------------------------------------------------------------
// TE: per-node time encoding, 256 cols (first 128 = dup sin enc, rest zero).
// ---------------------------------------------------------------------------
__global__ __launch_bounds__(256)
void te_kernel(const float* __restrict__ ts, const float* __restrict__ wtemb,
               const float* __restrict__ btemb, u16* __restrict__ TE)
{
    const int idx4 = (blockIdx.x * 256 + threadIdx.x) * 4;   // over 8192*256
    const int n = idx4 >> 8;
    const int j = idx4 & 255;
    ushort4 ov;
    if (j < 128) {
        const int kb = j & 63;
        const float tt = ts[n];
        ov.x = f2bf(sinf(tt * wtemb[kb + 0] + btemb[kb + 0]));
        ov.y = f2bf(sinf(tt * wtemb[kb + 1] + btemb[kb + 1]));
        ov.z = f2bf(sinf(tt * wtemb[kb + 2] + btemb[kb + 2]));
        ov.w = f2bf(sinf(tt * wtemb[kb + 3] + btemb[kb + 3]));
    } else {
        ov.x = ov.y = ov.z = ov.w = 0;
    }
    *(ushort4*)(TE + idx4) = ov;
}

// ---------------------------------------------------------------------------
// prep_e: edge-attr gather/convert into chunk rows (r = 4*el+b), 256 cols
// (128 data + 128 zero pad). 8 rows per 256-thr block, 32 lanes x 8 cols.
// ---------------------------------------------------------------------------
__global__ __launch_bounds__(256)
void prep_e(const float* __restrict__ eattr, u16* __restrict__ Ae, int e0)
{
    const int t  = threadIdx.x;
    const int r  = blockIdx.x * 8 + (t >> 5);
    const int cl = (t & 31) * 8;
    const int el = r >> 2;
    const int b  = r & 3;
    const int ge = e0 + el;
    uint4 ov;
    if (ge < EE && cl < 128) {
        const float* src = eattr + ((size_t)b * EE + ge) * 128 + cl;
        const float4 a = *(const float4*)src;
        const float4 c = *(const float4*)(src + 4);
        ov.x = (u32)f2bf(a.x) | ((u32)f2bf(a.y) << 16);
        ov.y = (u32)f2bf(a.z) | ((u32)f2bf(a.w) << 16);
        ov.z = (u32)f2bf(c.x) | ((u32)f2bf(c.y) << 16);
        ov.w = (u32)f2bf(c.z) | ((u32)f2bf(c.w) << 16);
    } else {
        ov.x = ov.y = ov.z = ov.w = 0;
    }
    *(uint4*)(Ae + (size_t)r * 256 + cl) = ov;
}

// ---------------------------------------------------------------------------
// helpers
// ---------------------------------------------------------------------------
__global__ __launch_bounds__(256)
void comb_w_bf(const float* __restrict__ Wa, const float* __restrict__ Wb,
               u16* __restrict__ out, int Kin, int ostride)
{
    const int idx  = blockIdx.x * 256 + threadIdx.x;
    const int c    = idx / Kin;
    const int kcol = idx - c * Kin;
    float acc = 0.f;
    for (int j = 0; j < CC; j++)
        acc += Wa[c * CC + j] * Wb[j * Kin + kcol];
    out[(size_t)c * ostride + kcol] = f2bf(acc);
}

__global__ __launch_bounds__(256)
void comb_b(const float* __restrict__ Wa, const float* __restrict__ bin,
            const float* __restrict__ ba, float* __restrict__ bout)
{
    const int c = blockIdx.x * 256 + threadIdx.x;
    float acc = ba[c];
    for (int j = 0; j < CC; j++)
        acc += Wa[c * CC + j] * bin[j];
    bout[c] = acc;
}

__global__ __launch_bounds__(256)
void cvt_bf(const float* __restrict__ in, u16* __restrict__ out, int n)
{
    const int i = (blockIdx.x * 256 + threadIdx.x) * 4;
    if (i < n) {
        const float4 v = *(const float4*)(in + i);
        ushort4 ov;
        ov.x = f2bf(v.x); ov.y = f2bf(v.y); ov.z = f2bf(v.z); ov.w = f2bf(v.w);
        *(ushort4*)(out + i) = ov;
    }
}

__global__ __launch_bounds__(256)
void zero_u16(u16* __restrict__ p, int n)
{
    const int i = blockIdx.x * 256 + threadIdx.x;
    if (i < n) p[i] = 0;
}

__global__ __launch_bounds__(256)
void copy_f32(const float* __restrict__ in, float* __restrict__ out, int n)
{
    const int i = blockIdx.x * 256 + threadIdx.x;
    if (i < n) out[i] = in[i];
}

// ---------------------------------------------------------------------------
// attn_fused: batch-axis attention with q/k gathered from per-node tables.
// q[r] = P[s][512:1024] + P[t][1536:2048] ; k[r] = KLR[s][0:512]+KLR[t][512:];
// v from kvv. Block = 4 edges x 64 lanes; ctx -> An.
// ---------------------------------------------------------------------------
__global__ __launch_bounds__(256)
void attn_fused(const u16* __restrict__ P, const u16* __restrict__ KLR,
                const u16* __restrict__ kvv, const int* __restrict__ ei,
                u16* __restrict__ ctx, int e0)
{
    const int el   = blockIdx.x * 4 + (threadIdx.x >> 6);
    const int ge   = e0 + el;
    const int lane = threadIdx.x & 63;
    const int off  = (lane >> 3) * 64 + (lane & 7) * 8;

    float qf[4][8], kf[4][8], vf[4][8];
    #pragma unroll
    for (int l = 0; l < 4; l++) {
        int s, t;
        if (ge < EE) {
            s = ei[(l * 2 + 0) * EE + ge];
            t = ei[(l * 2 + 1) * EE + ge];
        } else {
            s = t = ge - EE;
        }
        const size_t ns = (size_t)(l * NN + s);
        const size_t nt = (size_t)(l * NN + t);
        const uint4 qs = *(const uint4*)(P + ns * 2048 + 512 + off);
        const uint4 qt = *(const uint4*)(P + nt * 2048 + 1536 + off);
        const uint4 ks = *(const uint4*)(KLR + ns * 1024 + off);
        const uint4 kt = *(const uint4*)(KLR + nt * 1024 + 512 + off);
        const uint4 vx = *(const uint4*)(kvv + (size_t)(4 * el + l) * 512 + off);
        const u32 qa[4] = {qs.x, qs.y, qs.z, qs.w};
        const u32 qb[4] = {qt.x, qt.y, qt.z, qt.w};
        const u32 ka[4] = {ks.x, ks.y, ks.z, ks.w};
        const u32 kb[4] = {kt.x, kt.y, kt.z, kt.w};
        const u32 va[4] = {vx.x, vx.y, vx.z, vx.w};
        #pragma unroll
        for (int p = 0; p < 4; p++) {
            qf[l][2*p]   = bf2f((u16)qa[p])         + bf2f((u16)qb[p]);
            qf[l][2*p+1] = bf2f((u16)(qa[p] >> 16)) + bf2f((u16)(qb[p] >> 16));
            kf[l][2*p]   = bf2f((u16)ka[p])         + bf2f((u16)kb[p]);
            kf[l][2*p+1] = bf2f((u16)(ka[p] >> 16)) + bf2f((u16)(kb[p] >> 16));
            vf[l][2*p]   = bf2f((u16)va[p]);
            vf[l][2*p+1] = bf2f((u16)(va[p] >> 16));
        }
    }

    float sc[4][4];
    #pragma unroll
    for (int l = 0; l < 4; l++) {
        #pragma unroll
        for (int m = 0; m < 4; m++) {
            float p = 0.f;
            #pragma unroll
            for (int d = 0; d < 8; d++) p += qf[l][d] * kf[m][d];
            p += __shfl_xor(p, 1, 64);
            p += __shfl_xor(p, 2, 64);
            p += __shfl_xor(p, 4, 64);
            sc[l][m] = p * 0.125f;
        }
    }

    #pragma unroll
    for (int l = 0; l < 4; l++) {
        const float mx = fmaxf(fmaxf(sc[l][0], sc[l][1]), fmaxf(sc[l][2], sc[l][3]));
        float a[4], s = 0.f;
        #pragma unroll
        for (int m = 0; m < 4; m++) { a[m] = __expf(sc[l][m] - mx); s += a[m]; }
        const float inv = 1.0f / s;
        float cv[8];
        #pragma unroll
        for (int d = 0; d < 8; d++) {
            cv[d] = (a[0] * vf[0][d] + a[1] * vf[1][d] +
                     a[2] * vf[2][d] + a[3] * vf[3][d]) * inv;
        }
        ushort4 o0, o1;
        o0.x = f2bf(cv[0]); o0.y = f2bf(cv[1]); o0.z = f2bf(cv[2]); o0.w = f2bf(cv[3]);
        o1.x = f2bf(cv[4]); o1.y = f2bf(cv[5]); o1.z = f2bf(cv[6]); o1.w = f2bf(cv[7]);
        u16* crow = ctx + (size_t)(4 * el + l) * 512 + off;
        *(ushort4*)crow       = o0;
        *(ushort4*)(crow + 4) = o1;
    }
}

// ---------------------------------------------------------------------------
// ln1_fused (wave-per-row): out1 = LN(nodef + attn_out) -> bf16,
// nodef[r] = P[s][0:512] + P[t][1024:1536] gathered on the fly.
// ---------------------------------------------------------------------------
__global__ __launch_bounds__(256)
void ln1_fused(const u16* __restrict__ P, const u16* __restrict__ aout,
               const int* __restrict__ ei,
               const float* __restrict__ g, const float* __restrict__ be,
               u16* __restrict__ outb, int e0)
{
    const int r    = blockIdx.x * 4 + (threadIdx.x >> 6);
    const int lane = threadIdx.x & 63;
    const int c    = lane * 8;
    const int el   = r >> 2;
    const int b    = r & 3;
    const int ge   = e0 + el;

    int s, t;
    if (ge < EE) {
        s = ei[(b * 2 + 0) * EE + ge];
        t = ei[(b * 2 + 1) * EE + ge];
    } else {
        s = t = ge - EE;
    }

    const uint4 nfs = *(const uint4*)(P + (size_t)(b * NN + s) * 2048 + c);
    const uint4 nft = *(const uint4*)(P + (size_t)(b * NN + t) * 2048 + 1024 + c);
    const uint4 ao  = *(const uint4*)(aout + (size_t)r * 512 + c);
    const u32 na[4] = {nfs.x, nfs.y, nfs.z, nfs.w};
    const u32 nb[4] = {nft.x, nft.y, nft.z, nft.w};
    const u32 aa[4] = {ao.x, ao.y, ao.z, ao.w};

    float v[8];
    #pragma unroll
    for (int p = 0; p < 4; p++) {
        v[2*p]   = bf2f((u16)na[p])         + bf2f((u16)nb[p])         + bf2f((u16)aa[p]);
        v[2*p+1] = bf2f((u16)(na[p] >> 16)) + bf2f((u16)(nb[p] >> 16)) + bf2f((u16)(aa[p] >> 16));
    }

    float sum = 0.f;
    #pragma unroll
    for (int p = 0; p < 8; p++) sum += v[p];
    #pragma unroll
    for (int o = 32; o; o >>= 1) sum += __shfl_xor(sum, o, 64);
    const float mean = sum * (1.0f / 512.0f);

    float d[8], vs = 0.f;
    #pragma unroll
    for (int p = 0; p < 8; p++) { d[p] = v[p] - mean; vs += d[p] * d[p]; }
    #pragma unroll
    for (int o = 32; o; o >>= 1) vs += __shfl_xor(vs, o, 64);
    const float rstd = rsqrtf(vs * (1.0f / 512.0f) + 1e-5f);

    const float4 g0 = *(const float4*)(g + c),  g1 = *(const float4*)(g + c + 4);
    const float4 b0 = *(const float4*)(be + c), b1 = *(const float4*)(be + c + 4);
    const float gg[8] = {g0.x, g0.y, g0.z, g0.w, g1.x, g1.y, g1.z, g1.w};
    const float bb[8] = {b0.x, b0.y, b0.z, b0.w, b1.x, b1.y, b1.z, b1.w};

    uint4 ov;
    u32 w[4];
    #pragma unroll
    for (int p = 0; p < 4; p++) {
        const float y0 = d[2*p]   * rstd * gg[2*p]   + bb[2*p];
        const float y1 = d[2*p+1] * rstd * gg[2*p+1] + bb[2*p+1];
        w[p] = (u32)f2bf(y0) | ((u32)f2bf(y1) << 16);
    }
    ov.x = w[0]; ov.y = w[1]; ov.z = w[2]; ov.w = w[3];
    *(uint4*)(outb + (size_t)r * 512 + c) = ov;
}

// ---------------------------------------------------------------------------
// ln2 (wave-per-row): d_out[grow] = LN(out1 + ffn), f32 out.
// ---------------------------------------------------------------------------
__global__ __launch_bounds__(256)
void ln2_kernel(const u16* __restrict__ out1, const u16* __restrict__ ffn,
                const float* __restrict__ g, const float* __restrict__ be,
                float* __restrict__ out, int e0)
{
    const int r    = blockIdx.x * 4 + (threadIdx.x >> 6);
    const int lane = threadIdx.x & 63;
    const int c    = lane * 8;

    const uint4 o1 = *(const uint4*)(out1 + (size_t)r * 512 + c);
    const uint4 ff = *(const uint4*)(ffn  + (size_t)r * 512 + c);
    const u32 oa[4] = {o1.x, o1.y, o1.z, o1.w};
    const u32 fa[4] = {ff.x, ff.y, ff.z, ff.w};

    float v[8];
    #pragma unroll
    for (int p = 0; p < 4; p++) {
        v[2*p]   = bf2f((u16)oa[p])         + bf2f((u16)fa[p]);
        v[2*p+1] = bf2f((u16)(oa[p] >> 16)) + bf2f((u16)(fa[p] >> 16));
    }

    float s = 0.f;
    #pragma unroll
    for (int p = 0; p < 8; p++) s += v[p];
    #pragma unroll
    for (int o = 32; o; o >>= 1) s += __shfl_xor(s, o, 64);
    const float mean = s * (1.0f / 512.0f);

    float d[8], vs = 0.f;
    #pragma unroll
    for (int p = 0; p < 8; p++) { d[p] = v[p] - mean; vs += d[p] * d[p]; }
    #pragma unroll
    for (int o = 32; o; o >>= 1) vs += __shfl_xor(vs, o, 64);
    const float rstd = rsqrtf(vs * (1.0f / 512.0f) + 1e-5f);

    const float4 g0 = *(const float4*)(g + c),  g1 = *(const float4*)(g + c + 4);
    const float4 b0 = *(const float4*)(be + c), b1 = *(const float4*)(be + c + 4);

    const int el = r >> 2;
    const int b  = r & 3;
    float* orow = out + ((size_t)b * LL + e0 + el) * CC + c;
    float4 y0, y1;
    y0.x = d[0] * rstd * g0.x + b0.x;
    y0.y = d[1] * rstd * g0.y + b0.y;
    y0.z = d[2] * rstd * g0.z + b0.z;
    y0.w = d[3] * rstd * g0.w + b0.w;
    y1.x = d[4] * rstd * g1.x + b1.x;
    y1.y = d[5] * rstd * g1.y + b1.y;
    y1.z = d[6] * rstd * g1.z + b1.z;
    y1.w = d[7] * rstd * g1.w + b1.w;
    *(float4*)(orow)     = y0;
    *(float4*)(orow + 4) = y1;
}

// ---------------------------------------------------------------------------
extern "C" void kernel_launch(void* const* d_in, const int* in_sizes, int n_in,
                              void* d_out, int out_size, void* d_ws, size_t ws_size,
                              hipStream_t stream)
{
    const float* x       = (const float*)d_in[0];
    const float* eattr   = (const float*)d_in[1];
    const float* ts      = (const float*)d_in[2];
    const float* W_node  = (const float*)d_in[3];
    const float* b_node  = (const float*)d_in[4];
    const float* W_temb  = (const float*)d_in[5];
    const float* b_temb  = (const float*)d_in[6];
    const float* W_timef = (const float*)d_in[7];
    const float* b_timef = (const float*)d_in[8];
    const float* W_edge  = (const float*)d_in[9];
    const float* b_edge  = (const float*)d_in[10];
    const float* Wq      = (const float*)d_in[11];
    const float* bq      = (const float*)d_in[12];
    const float* Wk      = (const float*)d_in[13];
    const float* bk      = (const float*)d_in[14];
    const float* Wv      = (const float*)d_in[15];
    const float* bv      = (const float*)d_in[16];
    const float* Wo      = (const float*)d_in[17];
    const float* bo      = (const float*)d_in[18];
    const float* W1      = (const float*)d_in[19];
    const float* b1      = (const float*)d_in[20];
    const float* W2      = (const float*)d_in[21];
    const float* b2      = (const float*)d_in[22];
    const float* g1      = (const float*)d_in[23];
    const float* be1     = (const float*)d_in[24];
    const float* g2      = (const float*)d_in[25];
    const float* be2     = (const float*)d_in[26];
    const int*   ei      = (const int*)d_in[27];

    float* out = (float*)d_out;

    // ---- fixed region (u16 units) ----
    u16* wbig = (u16*)d_ws;                 // 2048x256  = 524288
    u16* wkt  = wbig + 524288;              // 1024x256  = 262144 (zero-padded)
    u16* wev  = wkt + 262144;               // 512x256   = 131072 (zero-padded)
    u16* wo   = wev + 131072;               // 512x512   = 262144
    u16* w1b  = wo + 262144;                // 2048x512  = 1048576
    u16* w2b  = w1b + 1048576;              // 512x2048  = 1048576
    u16* xb   = w2b + 1048576;              // 8192x256  = 2097152
    u16* TE   = xb + 2097152;               // 8192x256  = 2097152 (zero-padded)
    u16* P    = TE + 2097152;               // 8192x2048 = 16777216
    u16* KLR  = P + 16777216;               // 8192x1024 = 8388608
    float* bias2048 = (float*)(KLR + 8388608);  // 2048
    float* biasKLR  = bias2048 + 2048;          // 1024
    float* bev      = biasKLR + 1024;           // 512
    char*  cbase    = (char*)(bev + 512);
    const size_t fixedB = (size_t)(cbase - (char*)d_ws);

    // ---- chunk sizing: per edge = 4 rows x (256+512*3+2048) u16 = 30720 B --
    const size_t availB = (ws_size > fixedB) ? (ws_size - fixedB) : 0;
    int Ec = (int)(availB / 30720);
    Ec = (Ec / 64) * 64;                    // rows multiple of 256
    if (Ec > LL) Ec = LL;
    if (Ec < 64) Ec = 64;

    const size_t rmax = (size_t)4 * Ec;
    u16* Ae   = (u16*)cbase;                // rows x 256 (dedicated, no overlay)
    u16* kvv  = Ae + rmax * 256;            // rows x 512 (v)
    u16* An   = kvv + rmax * 512;           // rows x 512 (ctx -> out1)
    u16* aout = An + rmax * 512;            // rows x 512 (attn_out -> ffn)
    u16* hid  = aout + rmax * 512;          // rows x 2048

    const dim3 blk(256);
    const dim3 gblk(512);

    // ---- global precompute ----
    cvt_bf    <<<dim3(2048), blk, 0, stream>>>(x, xb, 2097152);
    build_wbig<<<dim3(2048), blk, 0, stream>>>(W_node, Wq, wbig);
    copy_f32  <<<dim3(2),    blk, 0, stream>>>(b_node, bias2048, 512);
    comb_b    <<<dim3(2),    blk, 0, stream>>>(Wq, b_node, bq, bias2048 + 512);
    zero_u16  <<<dim3(8),    blk, 0, stream>>>((u16*)(bias2048 + 1024), 2048);
    gemm_mfma<false><<<dim3(8, 32), gblk, 0, stream>>>(xb, wbig, bias2048, P, 2048, 256);

    te_kernel <<<dim3(2048), blk, 0, stream>>>(ts, W_temb, b_temb, TE);
    build_wkt <<<dim3(1024), blk, 0, stream>>>(Wk, W_timef, wkt);
    comb_b    <<<dim3(2),    blk, 0, stream>>>(Wk, b_timef, bk, biasKLR);
    zero_u16  <<<dim3(4),    blk, 0, stream>>>((u16*)(biasKLR + 512), 1024);
    gemm_mfma<false><<<dim3(4, 32), gblk, 0, stream>>>(TE, wkt, biasKLR, KLR, 1024, 256);

    zero_u16  <<<dim3(512),  blk, 0, stream>>>(wev, 131072);
    comb_w_bf <<<dim3(256),  blk, 0, stream>>>(Wv, W_edge, wev, 128, 256);
    comb_b    <<<dim3(2),    blk, 0, stream>>>(Wv, b_edge, bv, bev);
    cvt_bf    <<<dim3(256),  blk, 0, stream>>>(Wo, wo,  262144);
    cvt_bf    <<<dim3(1024), blk, 0, stream>>>(W1, w1b, 1048576);
    cvt_bf    <<<dim3(1024), blk, 0, stream>>>(W2, w2b, 1048576);

    for (int e0 = 0; e0 < LL; e0 += Ec) {
        int ec = LL - e0; if (ec > Ec) ec = Ec;
        const int rows = 4 * ec;
        const int gy = rows / 256;

        prep_e<<<dim3(rows / 8), blk, 0, stream>>>(eattr, Ae, e0);

        // v = Ae @ wev^T + bev   (K padded to 256, NT=8)
        gemm_mfma<false><<<dim3(2, gy), gblk, 0, stream>>>(Ae, wev, bev, kvv, 512, 256);

        // attention with gathered q/k ; ctx -> An
        attn_fused<<<dim3(ec / 4), blk, 0, stream>>>(P, KLR, kvv, ei, An, e0);

        // attn_out = ctx @ Wo^T + bo ; out1 = LN(gathered nodef + attn_out)
        gemm_mfma<false><<<dim3(2, gy), gblk, 0, stream>>>(An, wo, bo, aout, 512, 512);
        ln1_fused<<<dim3(rows / 4), blk, 0, stream>>>(P, aout, ei, g1, be1, An, e0);

        // FFN
        gemm_mfma<true ><<<dim3(8, gy), gblk, 0, stream>>>(An,  w1b, b1, hid, 2048, 512);
        gemm_mfma<false><<<dim3(2, gy), gblk, 0, stream>>>(hid, w2b, b2, aout, 512, 2048);

        ln2_kernel<<<dim3(rows / 4), blk, 0, stream>>>(An, aout, g2, be2, out, e0);
    }
}

// Round 14
// 1190.668 us; speedup vs baseline: 5.0933x; 5.0933x over previous
//
#include <hip/hip_runtime.h>
#include <math.h>

#define BB 4
#define NN 2048
#define EE 16384
#define LL (EE + NN)      // 18432
#define ND_ 256
#define ED_ 128
#define TD_ 64
#define CC 512
#define HH 8
#define DH_ 64
#define C4 2048

typedef unsigned short u16;
typedef unsigned int u32;
typedef __bf16 bhalf8 __attribute__((ext_vector_type(8)));
typedef float f32x4 __attribute__((ext_vector_type(4)));

__device__ __forceinline__ u16 f2bf(float f) {
    union { float f; unsigned u; } c; c.f = f;
    const unsigned r = (c.u + 0x7fffu + ((c.u >> 16) & 1u)) >> 16;   // RNE
    return (u16)r;
}
__device__ __forceinline__ u16 f2bf_hw(float f) {      // native cvt (RNE)
    __bf16 h = (__bf16)f;
    union { __bf16 h; u16 u; } c; c.h = h; return c.u;
}
__device__ __forceinline__ float bf2f(u16 u) {
    union { unsigned u; float f; } c; c.u = ((unsigned)u) << 16; return c.f;
}
// tanh-form GELU: |err vs exact-erf gelu| ~3e-4, far below bf16 rounding
__device__ __forceinline__ float gelu_fast(float v) {
    const float u = v * (0.7978845608f + 0.0356774081f * v * v);
    const float e = __expf(2.0f * u);
    const float t = 1.0f - 2.0f / (e + 1.0f);
    return 0.5f * v * (1.0f + t);
}

#define GLD16(gp, lp) __builtin_amdgcn_global_load_lds( \
    (const __attribute__((address_space(1))) unsigned int*)(gp), \
    (__attribute__((address_space(3))) unsigned int*)(lp), 16, 0, 0)

// ---------------------------------------------------------------------------
// bf16 MFMA GEMM — 128x128 tile, BK=32, 4 waves (2x2, 64x64 each):
//   Y[M x N](bf16) = A[M x K] @ W[N x K]^T + bias(f32)
// Register budget by design: acc[4][4]=64 + ~70 VGPR => ~3 waves/SIMD TLP
// (round-13 lesson: 128-reg acc tiles cannot exceed 2 waves/SIMD; forcing
// launch_bounds minimums causes catastrophic acc spill — none forced here).
// Counted-vmcnt pipeline (stage t+2 after barrier, s_waitcnt vmcnt(4), never
// 0 in steady state). Conflict-free BK=32 swizzle (round-13 PMC: 0 conflicts):
// stored chunk s = c ^ ((r>>1)&3); staging source chunk (t&3)^((t>>3)&3),
// LDS dest linear (rule #21). M%128==0, N%128==0, K%64==0 (NT>=8 here).
// ---------------------------------------------------------------------------
template<bool GELU>
__global__ __launch_bounds__(256)
void gemm_mfma(const u16* __restrict__ A, const u16* __restrict__ W,
               const float* __restrict__ bias, u16* __restrict__ Y,
               int N, int K)
{
    __shared__ u16 As[2][4096];   // 128 rows x 32 bf16 per buffer (8 KB)
    __shared__ u16 Bs[2][4096];

    // bijective XCD-chunked swizzle (m204)
    const int o    = blockIdx.y * gridDim.x + blockIdx.x;
    const int nwg  = gridDim.x * gridDim.y;
    const int xcd  = o & 7;
    const int qq   = nwg >> 3, rr = nwg & 7;
    const int wg   = (xcd < rr ? xcd * (qq + 1) : rr * (qq + 1) + (xcd - rr) * qq) + (o >> 3);
    const int bx   = wg % gridDim.x;
    const int by   = wg / gridDim.x;
    const int m0   = by * 128;
    const int n0   = bx * 128;

    const int tid  = threadIdx.x;
    const int lane = tid & 63;
    const int wid  = tid >> 6;          // 0..3
    const int wm   = wid >> 1;          // wave row: 2 x 64 rows
    const int wn   = wid & 1;           // wave col: 2 x 64 cols

    // staging: thread t -> LDS rows t>>2 and 64+(t>>2), chunk t&3 (linear
    // dest). Inverse-swizzled global source chunk: (t&3) ^ ((t>>3)&3)
    // ((r>>1)&3 is identical for r and r+64).
    const int csrc8 = (((tid & 3) ^ ((tid >> 3) & 3))) * 8;
    const size_t sK = (size_t)K;
    const u16* Agb = A + (size_t)(m0 + (tid >> 2)) * sK + csrc8;
    const u16* Wgb = W + (size_t)(n0 + (tid >> 2)) * sK + csrc8;

    const int NT  = K >> 5;             // K-tiles of 32
    const int rlo = lane & 15;
    const int hi4 = lane >> 4;          // frag k-slice 0..3

#define STAGE(kt, buf) do {                                      \
    const u16* _ga = Agb + (size_t)(kt) * 32;                    \
    const u16* _gb = Wgb + (size_t)(kt) * 32;                    \
    u16* _la = &As[buf][tid * 8];                                \
    u16* _lb = &Bs[buf][tid * 8];                                \
    GLD16(_ga,           _la);                                   \
    GLD16(_ga + 64 * sK, _la + 2048);                            \
    GLD16(_gb,           _lb);                                   \
    GLD16(_gb + 64 * sK, _lb + 2048);                            \
} while (0)

// read: row R, k-slice hi4 -> stored chunk hi4 ^ ((R>>1)&3)
#define RDX(buf, R) (*(const bhalf8*)&(buf)[(R) * 32 + ((hi4 ^ (((R) >> 1) & 3)) << 3)])

    f32x4 acc[4][4] = {};

    // prologue: tiles 0 and 1 in flight; wait for tile 0 only (vmcnt(4))
    STAGE(0, 0);
    STAGE(1, 1);
    asm volatile("s_waitcnt vmcnt(4)" ::: "memory");
    __builtin_amdgcn_s_barrier();
    __builtin_amdgcn_sched_barrier(0);

    for (int t = 0; t < NT; ++t) {
        const u16* as = &As[t & 1][0];
        const u16* bs = &Bs[t & 1][0];

        bhalf8 a[4], b[4];
        #pragma unroll
        for (int i = 0; i < 4; ++i) {
            const int R = wm * 64 + i * 16 + rlo;
            a[i] = RDX(as, R);
        }
        #pragma unroll
        for (int j = 0; j < 4; ++j) {
            const int R = wn * 64 + j * 16 + rlo;
            b[j] = RDX(bs, R);
        }

        __builtin_amdgcn_s_setprio(1);
        #pragma unroll
        for (int i = 0; i < 4; ++i)
            #pragma unroll
            for (int j = 0; j < 4; ++j)   // swapped operands: row-major D
                acc[i][j] = __builtin_amdgcn_mfma_f32_16x16x32_bf16(b[j], a[i], acc[i][j], 0, 0, 0);
        __builtin_amdgcn_s_setprio(0);

        if (t == NT - 1) break;
        __builtin_amdgcn_sched_barrier(0);
        __builtin_amdgcn_s_barrier();            // all waves done reading buf[cur]
        __builtin_amdgcn_sched_barrier(0);
        if (t + 2 < NT) {
            STAGE(t + 2, t & 1);                 // refill just-freed buffer
            asm volatile("s_waitcnt vmcnt(4)" ::: "memory");   // t+1 landed; t+2 in flight
        } else {
            asm volatile("s_waitcnt vmcnt(0)" ::: "memory");   // drain t+1
        }
        __builtin_amdgcn_s_barrier();            // tile t+1 visible to all waves
        __builtin_amdgcn_sched_barrier(0);
    }
#undef STAGE
#undef RDX

    // Epilogue: row = m0+wm*64+i*16+(lane&15); cols = n0+wn*64+j*16+(lane>>4)*4
    const int row0 = m0 + wm * 64;
    const int col0 = n0 + wn * 64;
    const int rq   = (lane >> 4) * 4;
    float4 bi[4];
    #pragma unroll
    for (int j = 0; j < 4; ++j)
        bi[j] = *(const float4*)(bias + col0 + j * 16 + rq);

    #pragma unroll
    for (int i = 0; i < 4; ++i) {
        const int gr = row0 + i * 16 + rlo;
        u16* yrow = Y + (size_t)gr * N + col0;
        #pragma unroll
        for (int j = 0; j < 4; ++j) {
            float v0 = acc[i][j][0] + bi[j].x;
            float v1 = acc[i][j][1] + bi[j].y;
            float v2 = acc[i][j][2] + bi[j].z;
            float v3 = acc[i][j][3] + bi[j].w;
            if constexpr (GELU) {
                v0 = gelu_fast(v0); v1 = gelu_fast(v1);
                v2 = gelu_fast(v2); v3 = gelu_fast(v3);
            }
            ushort4 ov;
            ov.x = f2bf_hw(v0); ov.y = f2bf_hw(v1);
            ov.z = f2bf_hw(v2); ov.w = f2bf_hw(v3);
            *(ushort4*)(yrow + j * 16 + rq) = ov;
        }
    }
}

// ---------------------------------------------------------------------------
// Wbig builder: 2048x256 bf16.
// rows 0..511 = W_node[:,0:256]; 512..1023 = (Wq@W_node)[:,0:256];
// 1024..1535 = W_node[:,256:512]; 1536..2047 = (Wq@W_node)[:,256:512]
// ---------------------------------------------------------------------------
__global__ __launch_bounds__(256)
void build_wbig(const float* __restrict__ Wn, const float* __restrict__ Wq,
                u16* __restrict__ out)
{
    const int idx = blockIdx.x * 256 + threadIdx.x;   // 524288
    const int R = idx >> 8;
    const int k = idx & 255;
    float v;
    if (R < 512) {
        v = Wn[R * 512 + k];
    } else if (R < 1024) {
        const int c = R - 512; float a = 0.f;
        for (int j = 0; j < 512; j++) a += Wq[c * 512 + j] * Wn[j * 512 + k];
        v = a;
    } else if (R < 1536) {
        v = Wn[(R - 1024) * 512 + 256 + k];
    } else {
        const int c = R - 1536; float a = 0.f;
        for (int j = 0; j < 512; j++) a += Wq[c * 512 + j] * Wn[j * 512 + 256 + k];
        v = a;
    }
    out[idx] = f2bf(v);
}

// ---------------------------------------------------------------------------
// Wkt builder: 1024x256 bf16 (cols 128..255 zero padding), block-diag of
// wtk = Wk@W_timef: rows 0..511: [wtk[:,0:64] | 0...] ; 512..1023: [0 | wtk[:,64:128] | 0pad]
// ---------------------------------------------------------------------------
__global__ __launch_bounds__(256)
void build_wkt(const float* __restrict__ Wk, const float* __restrict__ Wtf,
               u16* __restrict__ out)
{
    const int idx = blockIdx.x * 256 + threadIdx.x;   // 262144
    const int R = idx >> 8;
    const int k = idx & 255;
    float v = 0.f;
    const bool live = (k < 128) && ((R < 512) ? (k < 64) : (k >= 64));
    if (live) {
        const int c = (R < 512) ? R : R - 512;
        float a = 0.f;
        for (int j = 0; j < 512; j++) a += Wk[c * 512 + j] * Wtf[j * 128 + k];
        v = a;
    }
    out[idx] = f2bf(v);
}

// ---------------------------------------------------------------------------
// TE: per-node time encoding, 256 cols (first 128 = dup sin enc, rest zero).
// ---------------------------------------------------------------------------
__global__ __launch_bounds__(256)
void te_kernel(const float* __restrict__ ts, const float* __restrict__ wtemb,
               const float* __restrict__ btemb, u16* __restrict__ TE)
{
    const int idx4 = (blockIdx.x * 256 + threadIdx.x) * 4;   // over 8192*256
    const int n = idx4 >> 8;
    const int j = idx4 & 255;
    ushort4 ov;
    if (j < 128) {
        const int kb = j & 63;
        const float tt = ts[n];
        ov.x = f2bf(sinf(tt * wtemb[kb + 0] + btemb[kb + 0]));
        ov.y = f2bf(sinf(tt * wtemb[kb + 1] + btemb[kb + 1]));
        ov.z = f2bf(sinf(tt * wtemb[kb + 2] + btemb[kb + 2]));
        ov.w = f2bf(sinf(tt * wtemb[kb + 3] + btemb[kb + 3]));
    } else {
        ov.x = ov.y = ov.z = ov.w = 0;
    }
    *(ushort4*)(TE + idx4) = ov;
}

// ---------------------------------------------------------------------------
// prep_e: edge-attr gather/convert into chunk rows (r = 4*el+b), 256 cols
// (128 data + 128 zero pad). 8 rows per 256-thr block, 32 lanes x 8 cols.
// ---------------------------------------------------------------------------
__global__ __launch_bounds__(256)
void prep_e(const float* __restrict__ eattr, u16* __restrict__ Ae, int e0)
{
    const int t  = threadIdx.x;
    const int r  = blockIdx.x * 8 + (t >> 5);
    const int cl = (t & 31) * 8;
    const int el = r >> 2;
    const int b  = r & 3;
    const int ge = e0 + el;
    uint4 ov;
    if (ge < EE && cl < 128) {
        const float* src = eattr + ((size_t)b * EE + ge) * 128 + cl;
        const float4 a = *(const float4*)src;
        const float4 c = *(const float4*)(src + 4);
        ov.x = (u32)f2bf(a.x) | ((u32)f2bf(a.y) << 16);
        ov.y = (u32)f2bf(a.z) | ((u32)f2bf(a.w) << 16);
        ov.z = (u32)f2bf(c.x) | ((u32)f2bf(c.y) << 16);
        ov.w = (u32)f2bf(c.z) | ((u32)f2bf(c.w) << 16);
    } else {
        ov.x = ov.y = ov.z = ov.w = 0;
    }
    *(uint4*)(Ae + (size_t)r * 256 + cl) = ov;
}

// ---------------------------------------------------------------------------
// helpers
// ---------------------------------------------------------------------------
__global__ __launch_bounds__(256)
void comb_w_bf(const float* __restrict__ Wa, const float* __restrict__ Wb,
               u16* __restrict__ out, int Kin, int ostride)
{
    const int idx  = blockIdx.x * 256 + threadIdx.x;
    const int c    = idx / Kin;
    const int kcol = idx - c * Kin;
    float acc = 0.f;
    for (int j = 0; j < CC; j++)
        acc += Wa[c * CC + j] * Wb[j * Kin + kcol];
    out[(size_t)c * ostride + kcol] = f2bf(acc);
}

__global__ __launch_bounds__(256)
void comb_b(const float* __restrict__ Wa, const float* __restrict__ bin,
            const float* __restrict__ ba, float* __restrict__ bout)
{
    const int c = blockIdx.x * 256 + threadIdx.x;
    float acc = ba[c];
    for (int j = 0; j < CC; j++)
        acc += Wa[c * CC + j] * bin[j];
    bout[c] = acc;
}

__global__ __launch_bounds__(256)
void cvt_bf(const float* __restrict__ in, u16* __restrict__ out, int n)
{
    const int i = (blockIdx.x * 256 + threadIdx.x) * 4;
    if (i < n) {
        const float4 v = *(const float4*)(in + i);
        ushort4 ov;
        ov.x = f2bf(v.x); ov.y = f2bf(v.y); ov.z = f2bf(v.z); ov.w = f2bf(v.w);
        *(ushort4*)(out + i) = ov;
    }
}

__global__ __launch_bounds__(256)
void zero_u16(u16* __restrict__ p, int n)
{
    const int i = blockIdx.x * 256 + threadIdx.x;
    if (i < n) p[i] = 0;
}

__global__ __launch_bounds__(256)
void copy_f32(const float* __restrict__ in, float* __restrict__ out, int n)
{
    const int i = blockIdx.x * 256 + threadIdx.x;
    if (i < n) out[i] = in[i];
}

// ---------------------------------------------------------------------------
// attn_fused: batch-axis attention with q/k gathered from per-node tables.
// q[r] = P[s][512:1024] + P[t][1536:2048] ; k[r] = KLR[s][0:512]+KLR[t][512:];
// v from kvv. Block = 4 edges x 64 lanes; ctx -> An.
// ---------------------------------------------------------------------------
__global__ __launch_bounds__(256)
void attn_fused(const u16* __restrict__ P, const u16* __restrict__ KLR,
                const u16* __restrict__ kvv, const int* __restrict__ ei,
                u16* __restrict__ ctx, int e0)
{
    const int el   = blockIdx.x * 4 + (threadIdx.x >> 6);
    const int ge   = e0 + el;
    const int lane = threadIdx.x & 63;
    const int off  = (lane >> 3) * 64 + (lane & 7) * 8;

    float qf[4][8], kf[4][8], vf[4][8];
    #pragma unroll
    for (int l = 0; l < 4; l++) {
        int s, t;
        if (ge < EE) {
            s = ei[(l * 2 + 0) * EE + ge];
            t = ei[(l * 2 + 1) * EE + ge];
        } else {
            s = t = ge - EE;
        }
        const size_t ns = (size_t)(l * NN + s);
        const size_t nt = (size_t)(l * NN + t);
        const uint4 qs = *(const uint4*)(P + ns * 2048 + 512 + off);
        const uint4 qt = *(const uint4*)(P + nt * 2048 + 1536 + off);
        const uint4 ks = *(const uint4*)(KLR + ns * 1024 + off);
        const uint4 kt = *(const uint4*)(KLR + nt * 1024 + 512 + off);
        const uint4 vx = *(const uint4*)(kvv + (size_t)(4 * el + l) * 512 + off);
        const u32 qa[4] = {qs.x, qs.y, qs.z, qs.w};
        const u32 qb[4] = {qt.x, qt.y, qt.z, qt.w};
        const u32 ka[4] = {ks.x, ks.y, ks.z, ks.w};
        const u32 kb[4] = {kt.x, kt.y, kt.z, kt.w};
        const u32 va[4] = {vx.x, vx.y, vx.z, vx.w};
        #pragma unroll
        for (int p = 0; p < 4; p++) {
            qf[l][2*p]   = bf2f((u16)qa[p])         + bf2f((u16)qb[p]);
            qf[l][2*p+1] = bf2f((u16)(qa[p] >> 16)) + bf2f((u16)(qb[p] >> 16));
            kf[l][2*p]   = bf2f((u16)ka[p])         + bf2f((u16)kb[p]);
            kf[l][2*p+1] = bf2f((u16)(ka[p] >> 16)) + bf2f((u16)(kb[p] >> 16));
            vf[l][2*p]   = bf2f((u16)va[p]);
            vf[l][2*p+1] = bf2f((u16)(va[p] >> 16));
        }
    }

    float sc[4][4];
    #pragma unroll
    for (int l = 0; l < 4; l++) {
        #pragma unroll
        for (int m = 0; m < 4; m++) {
            float p = 0.f;
            #pragma unroll
            for (int d = 0; d < 8; d++) p += qf[l][d] * kf[m][d];
            p += __shfl_xor(p, 1, 64);
            p += __shfl_xor(p, 2, 64);
            p += __shfl_xor(p, 4, 64);
            sc[l][m] = p * 0.125f;
        }
    }

    #pragma unroll
    for (int l = 0; l < 4; l++) {
        const float mx = fmaxf(fmaxf(sc[l][0], sc[l][1]), fmaxf(sc[l][2], sc[l][3]));
        float a[4], s = 0.f;
        #pragma unroll
        for (int m = 0; m < 4; m++) { a[m] = __expf(sc[l][m] - mx); s += a[m]; }
        const float inv = 1.0f / s;
        float cv[8];
        #pragma unroll
        for (int d = 0; d < 8; d++) {
            cv[d] = (a[0] * vf[0][d] + a[1] * vf[1][d] +
                     a[2] * vf[2][d] + a[3] * vf[3][d]) * inv;
        }
        ushort4 o0, o1;
        o0.x = f2bf(cv[0]); o0.y = f2bf(cv[1]); o0.z = f2bf(cv[2]); o0.w = f2bf(cv[3]);
        o1.x = f2bf(cv[4]); o1.y = f2bf(cv[5]); o1.z = f2bf(cv[6]); o1.w = f2bf(cv[7]);
        u16* crow = ctx + (size_t)(4 * el + l) * 512 + off;
        *(ushort4*)crow       = o0;
        *(ushort4*)(crow + 4) = o1;
    }
}

// ---------------------------------------------------------------------------
// ln1_fused (wave-per-row): out1 = LN(nodef + attn_out) -> bf16,
// nodef[r] = P[s][0:512] + P[t][1024:1536] gathered on the fly.
// ---------------------------------------------------------------------------
__global__ __launch_bounds__(256)
void ln1_fused(const u16* __restrict__ P, const u16* __restrict__ aout,
               const int* __restrict__ ei,
               const float* __restrict__ g, const float* __restrict__ be,
               u16* __restrict__ outb, int e0)
{
    const int r    = blockIdx.x * 4 + (threadIdx.x >> 6);
    const int lane = threadIdx.x & 63;
    const int c    = lane * 8;
    const int el   = r >> 2;
    const int b    = r & 3;
    const int ge   = e0 + el;

    int s, t;
    if (ge < EE) {
        s = ei[(b * 2 + 0) * EE + ge];
        t = ei[(b * 2 + 1) * EE + ge];
    } else {
        s = t = ge - EE;
    }

    const uint4 nfs = *(const uint4*)(P + (size_t)(b * NN + s) * 2048 + c);
    const uint4 nft = *(const uint4*)(P + (size_t)(b * NN + t) * 2048 + 1024 + c);
    const uint4 ao  = *(const uint4*)(aout + (size_t)r * 512 + c);
    const u32 na[4] = {nfs.x, nfs.y, nfs.z, nfs.w};
    const u32 nb[4] = {nft.x, nft.y, nft.z, nft.w};
    const u32 aa[4] = {ao.x, ao.y, ao.z, ao.w};

    float v[8];
    #pragma unroll
    for (int p = 0; p < 4; p++) {
        v[2*p]   = bf2f((u16)na[p])         + bf2f((u16)nb[p])         + bf2f((u16)aa[p]);
        v[2*p+1] = bf2f((u16)(na[p] >> 16)) + bf2f((u16)(nb[p] >> 16)) + bf2f((u16)(aa[p] >> 16));
    }

    float sum = 0.f;
    #pragma unroll
    for (int p = 0; p < 8; p++) sum += v[p];
    #pragma unroll
    for (int o = 32; o; o >>= 1) sum += __shfl_xor(sum, o, 64);
    const float mean = sum * (1.0f / 512.0f);

    float d[8], vs = 0.f;
    #pragma unroll
    for (int p = 0; p < 8; p++) { d[p] = v[p] - mean; vs += d[p] * d[p]; }
    #pragma unroll
    for (int o = 32; o; o >>= 1) vs += __shfl_xor(vs, o, 64);
    const float rstd = rsqrtf(vs * (1.0f / 512.0f) + 1e-5f);

    const float4 g0 = *(const float4*)(g + c),  g1 = *(const float4*)(g + c + 4);
    const float4 b0 = *(const float4*)(be + c), b1 = *(const float4*)(be + c + 4);
    const float gg[8] = {g0.x, g0.y, g0.z, g0.w, g1.x, g1.y, g1.z, g1.w};
    const float bb[8] = {b0.x, b0.y, b0.z, b0.w, b1.x, b1.y, b1.z, b1.w};

    uint4 ov;
    u32 w[4];
    #pragma unroll
    for (int p = 0; p < 4; p++) {
        const float y0 = d[2*p]   * rstd * gg[2*p]   + bb[2*p];
        const float y1 = d[2*p+1] * rstd * gg[2*p+1] + bb[2*p+1];
        w[p] = (u32)f2bf(y0) | ((u32)f2bf(y1) << 16);
    }
    ov.x = w[0]; ov.y = w[1]; ov.z = w[2]; ov.w = w[3];
    *(uint4*)(outb + (size_t)r * 512 + c) = ov;
}

// ---------------------------------------------------------------------------
// ln2 (wave-per-row): d_out[grow] = LN(out1 + ffn), f32 out.
// ---------------------------------------------------------------------------
__global__ __launch_bounds__(256)
void ln2_kernel(const u16* __restrict__ out1, const u16* __restrict__ ffn,
                const float* __restrict__ g, const float* __restrict__ be,
                float* __restrict__ out, int e0)
{
    const int r    = blockIdx.x * 4 + (threadIdx.x >> 6);
    const int lane = threadIdx.x & 63;
    const int c    = lane * 8;

    const uint4 o1 = *(const uint4*)(out1 + (size_t)r * 512 + c);
    const uint4 ff = *(const uint4*)(ffn  + (size_t)r * 512 + c);
    const u32 oa[4] = {o1.x, o1.y, o1.z, o1.w};
    const u32 fa[4] = {ff.x, ff.y, ff.z, ff.w};

    float v[8];
    #pragma unroll
    for (int p = 0; p < 4; p++) {
        v[2*p]   = bf2f((u16)oa[p])         + bf2f((u16)fa[p]);
        v[2*p+1] = bf2f((u16)(oa[p] >> 16)) + bf2f((u16)(fa[p] >> 16));
    }

    float s = 0.f;
    #pragma unroll
    for (int p = 0; p < 8; p++) s += v[p];
    #pragma unroll
    for (int o = 32; o; o >>= 1) s += __shfl_xor(s, o, 64);
    const float mean = s * (1.0f / 512.0f);

    float d[8], vs = 0.f;
    #pragma unroll
    for (int p = 0; p < 8; p++) { d[p] = v[p] - mean; vs += d[p] * d[p]; }
    #pragma unroll
    for (int o = 32; o; o >>= 1) vs += __shfl_xor(vs, o, 64);
    const float rstd = rsqrtf(vs * (1.0f / 512.0f) + 1e-5f);

    const float4 g0 = *(const float4*)(g + c),  g1 = *(const float4*)(g + c + 4);
    const float4 b0 = *(const float4*)(be + c), b1 = *(const float4*)(be + c + 4);

    const int el = r >> 2;
    const int b  = r & 3;
    float* orow = out + ((size_t)b * LL + e0 + el) * CC + c;
    float4 y0, y1;
    y0.x = d[0] * rstd * g0.x + b0.x;
    y0.y = d[1] * rstd * g0.y + b0.y;
    y0.z = d[2] * rstd * g0.z + b0.z;
    y0.w = d[3] * rstd * g0.w + b0.w;
    y1.x = d[4] * rstd * g1.x + b1.x;
    y1.y = d[5] * rstd * g1.y + b1.y;
    y1.z = d[6] * rstd * g1.z + b1.z;
    y1.w = d[7] * rstd * g1.w + b1.w;
    *(float4*)(orow)     = y0;
    *(float4*)(orow + 4) = y1;
}

// ---------------------------------------------------------------------------
extern "C" void kernel_launch(void* const* d_in, const int* in_sizes, int n_in,
                              void* d_out, int out_size, void* d_ws, size_t ws_size,
                              hipStream_t stream)
{
    const float* x       = (const float*)d_in[0];
    const float* eattr   = (const float*)d_in[1];
    const float* ts      = (const float*)d_in[2];
    const float* W_node  = (const float*)d_in[3];
    const float* b_node  = (const float*)d_in[4];
    const float* W_temb  = (const float*)d_in[5];
    const float* b_temb  = (const float*)d_in[6];
    const float* W_timef = (const float*)d_in[7];
    const float* b_timef = (const float*)d_in[8];
    const float* W_edge  = (const float*)d_in[9];
    const float* b_edge  = (const float*)d_in[10];
    const float* Wq      = (const float*)d_in[11];
    const float* bq      = (const float*)d_in[12];
    const float* Wk      = (const float*)d_in[13];
    const float* bk      = (const float*)d_in[14];
    const float* Wv      = (const float*)d_in[15];
    const float* bv      = (const float*)d_in[16];
    const float* Wo      = (const float*)d_in[17];
    const float* bo      = (const float*)d_in[18];
    const float* W1      = (const float*)d_in[19];
    const float* b1      = (const float*)d_in[20];
    const float* W2      = (const float*)d_in[21];
    const float* b2      = (const float*)d_in[22];
    const float* g1      = (const float*)d_in[23];
    const float* be1     = (const float*)d_in[24];
    const float* g2      = (const float*)d_in[25];
    const float* be2     = (const float*)d_in[26];
    const int*   ei      = (const int*)d_in[27];

    float* out = (float*)d_out;

    // ---- fixed region (u16 units) ----
    u16* wbig = (u16*)d_ws;                 // 2048x256  = 524288
    u16* wkt  = wbig + 524288;              // 1024x256  = 262144 (zero-padded)
    u16* wev  = wkt + 262144;               // 512x256   = 131072 (zero-padded)
    u16* wo   = wev + 131072;               // 512x512   = 262144
    u16* w1b  = wo + 262144;                // 2048x512  = 1048576
    u16* w2b  = w1b + 1048576;              // 512x2048  = 1048576
    u16* xb   = w2b + 1048576;              // 8192x256  = 2097152
    u16* TE   = xb + 2097152;               // 8192x256  = 2097152 (zero-padded)
    u16* P    = TE + 2097152;               // 8192x2048 = 16777216
    u16* KLR  = P + 16777216;               // 8192x1024 = 8388608
    float* bias2048 = (float*)(KLR + 8388608);  // 2048
    float* biasKLR  = bias2048 + 2048;          // 1024
    float* bev      = biasKLR + 1024;           // 512
    char*  cbase    = (char*)(bev + 512);
    const size_t fixedB = (size_t)(cbase - (char*)d_ws);

    // ---- chunk sizing: per edge = 4 rows x (256+512*3+2048) u16 = 30720 B --
    const size_t availB = (ws_size > fixedB) ? (ws_size - fixedB) : 0;
    int Ec = (int)(availB / 30720);
    Ec = (Ec / 64) * 64;                    // rows multiple of 256
    if (Ec > LL) Ec = LL;
    if (Ec < 64) Ec = 64;

    const size_t rmax = (size_t)4 * Ec;
    u16* Ae   = (u16*)cbase;                // rows x 256 (dedicated, no overlay)
    u16* kvv  = Ae + rmax * 256;            // rows x 512 (v)
    u16* An   = kvv + rmax * 512;           // rows x 512 (ctx -> out1)
    u16* aout = An + rmax * 512;            // rows x 512 (attn_out -> ffn)
    u16* hid  = aout + rmax * 512;          // rows x 2048

    const dim3 blk(256);

    // ---- global precompute ----
    cvt_bf    <<<dim3(2048), blk, 0, stream>>>(x, xb, 2097152);
    build_wbig<<<dim3(2048), blk, 0, stream>>>(W_node, Wq, wbig);
    copy_f32  <<<dim3(2),    blk, 0, stream>>>(b_node, bias2048, 512);
    comb_b    <<<dim3(2),    blk, 0, stream>>>(Wq, b_node, bq, bias2048 + 512);
    zero_u16  <<<dim3(8),    blk, 0, stream>>>((u16*)(bias2048 + 1024), 2048);
    gemm_mfma<false><<<dim3(16, 64), blk, 0, stream>>>(xb, wbig, bias2048, P, 2048, 256);

    te_kernel <<<dim3(2048), blk, 0, stream>>>(ts, W_temb, b_temb, TE);
    build_wkt <<<dim3(1024), blk, 0, stream>>>(Wk, W_timef, wkt);
    comb_b    <<<dim3(2),    blk, 0, stream>>>(Wk, b_timef, bk, biasKLR);
    zero_u16  <<<dim3(4),    blk, 0, stream>>>((u16*)(biasKLR + 512), 1024);
    gemm_mfma<false><<<dim3(8, 64), blk, 0, stream>>>(TE, wkt, biasKLR, KLR, 1024, 256);

    zero_u16  <<<dim3(512),  blk, 0, stream>>>(wev, 131072);
    comb_w_bf <<<dim3(256),  blk, 0, stream>>>(Wv, W_edge, wev, 128, 256);
    comb_b    <<<dim3(2),    blk, 0, stream>>>(Wv, b_edge, bv, bev);
    cvt_bf    <<<dim3(256),  blk, 0, stream>>>(Wo, wo,  262144);
    cvt_bf    <<<dim3(1024), blk, 0, stream>>>(W1, w1b, 1048576);
    cvt_bf    <<<dim3(1024), blk, 0, stream>>>(W2, w2b, 1048576);

    for (int e0 = 0; e0 < LL; e0 += Ec) {
        int ec = LL - e0; if (ec > Ec) ec = Ec;
        const int rows = 4 * ec;
        const int gy = rows / 128;

        prep_e<<<dim3(rows / 8), blk, 0, stream>>>(eattr, Ae, e0);

        // v = Ae @ wev^T + bev   (K padded to 256, NT=8)
        gemm_mfma<false><<<dim3(4, gy), blk, 0, stream>>>(Ae, wev, bev, kvv, 512, 256);

        // attention with gathered q/k ; ctx -> An
        attn_fused<<<dim3(ec / 4), blk, 0, stream>>>(P, KLR, kvv, ei, An, e0);

        // attn_out = ctx @ Wo^T + bo ; out1 = LN(gathered nodef + attn_out)
        gemm_mfma<false><<<dim3(4, gy), blk, 0, stream>>>(An, wo, bo, aout, 512, 512);
        ln1_fused<<<dim3(rows / 4), blk, 0, stream>>>(P, aout, ei, g1, be1, An, e0);

        // FFN
        gemm_mfma<true ><<<dim3(16, gy), blk, 0, stream>>>(An,  w1b, b1, hid, 2048, 512);
        gemm_mfma<false><<<dim3(4, gy),  blk, 0, stream>>>(hid, w2b, b2, aout, 512, 2048);

        ln2_kernel<<<dim3(rows / 4), blk, 0, stream>>>(An, aout, g2, be2, out, e0);
    }
}

// Round 15
// 1131.744 us; speedup vs baseline: 5.3585x; 1.0521x over previous
//
#include <hip/hip_runtime.h>
#include <math.h>

#define BB 4
#define NN 2048
#define EE 16384
#define LL (EE + NN)      // 18432
#define ND_ 256
#define ED_ 128
#define TD_ 64
#define CC 512
#define HH 8
#define DH_ 64
#define C4 2048

typedef unsigned short u16;
typedef unsigned int u32;
typedef __bf16 bhalf8 __attribute__((ext_vector_type(8)));
typedef float f32x4 __attribute__((ext_vector_type(4)));

__device__ __forceinline__ u16 f2bf(float f) {
    union { float f; unsigned u; } c; c.f = f;
    const unsigned r = (c.u + 0x7fffu + ((c.u >> 16) & 1u)) >> 16;   // RNE
    return (u16)r;
}
__device__ __forceinline__ u16 f2bf_hw(float f) {      // native cvt (RNE)
    __bf16 h = (__bf16)f;
    union { __bf16 h; u16 u; } c; c.h = h; return c.u;
}
__device__ __forceinline__ float bf2f(u16 u) {
    union { unsigned u; float f; } c; c.u = ((unsigned)u) << 16; return c.f;
}
// tanh-form GELU: |err vs exact-erf gelu| ~3e-4, far below bf16 rounding
__device__ __forceinline__ float gelu_fast(float v) {
    const float u = v * (0.7978845608f + 0.0356774081f * v * v);
    const float e = __expf(2.0f * u);
    const float t = 1.0f - 2.0f / (e + 1.0f);
    return 0.5f * v * (1.0f + t);
}

#define GLD16(gp, lp) __builtin_amdgcn_global_load_lds( \
    (const __attribute__((address_space(1))) unsigned int*)(gp), \
    (__attribute__((address_space(3))) unsigned int*)(lp), 16, 0, 0)

// ---------------------------------------------------------------------------
// bf16 MFMA GEMM — 8-phase schedule (round-12 configuration, measured best:
// 313 us on W1, replay-proven):
//   Y[M x N](bf16) = A[M x K] @ W[N x K]^T + bias(f32)
// 256x256 block, 512 thr = 8 waves, BK=64, dbuf 128 KB LDS, counted vmcnt(4),
// T2 XOR swizzle (0 bank conflicts). M%256==0, N%256==0, K%64==0, K>=256.
// ---------------------------------------------------------------------------
template<bool GELU>
__global__ __launch_bounds__(512, 2)
void gemm_mfma(const u16* __restrict__ A, const u16* __restrict__ W,
               const float* __restrict__ bias, u16* __restrict__ Y,
               int N, int K)
{
    __shared__ u16 As[2][16384];
    __shared__ u16 Bs[2][16384];

    const int o    = blockIdx.y * gridDim.x + blockIdx.x;
    const int nwg  = gridDim.x * gridDim.y;
    const int xcd  = o & 7;
    const int qq   = nwg >> 3, rr = nwg & 7;
    const int wg   = (xcd < rr ? xcd * (qq + 1) : rr * (qq + 1) + (xcd - rr) * qq) + (o >> 3);
    const int bx   = wg % gridDim.x;
    const int by   = wg / gridDim.x;
    const int m0   = by * 256;
    const int n0   = bx * 256;

    const int tid  = threadIdx.x;
    const int lane = tid & 63;
    const int wid  = tid >> 6;
    const int wm   = wid >> 2;
    const int wn   = wid & 3;

    const int swz8 = (((tid & 7) ^ ((tid >> 3) & 7))) * 8;
    const size_t sK = (size_t)K;
    const u16* Agb = A + (size_t)(m0 + (tid >> 3)) * sK + swz8;
    const u16* Wgb = W + (size_t)(n0 + (tid >> 3)) * sK + swz8;

    const int NT  = K >> 6;
    const int rlo = lane & 15;
    const int hi4 = lane >> 4;
    const int lk  = lane & 7;

#define STAGE_A(kt, h) do {                                      \
    const u16* _g = Agb + (size_t)(kt) * 64 + (size_t)(h) * 128 * sK; \
    u16* _l = &As[(kt) & 1][(h) * 8192 + tid * 8];               \
    GLD16(_g,           _l);                                     \
    GLD16(_g + 64 * sK, _l + 4096);                              \
} while (0)
#define STAGE_B(kt, h) do {                                      \
    const u16* _g = Wgb + (size_t)(kt) * 64 + (size_t)(h) * 128 * sK; \
    u16* _l = &Bs[(kt) & 1][(h) * 8192 + tid * 8];               \
    GLD16(_g,           _l);                                     \
    GLD16(_g + 64 * sK, _l + 4096);                              \
} while (0)

#define SWZOFF(ks) (((((ks) << 2) | hi4) ^ lk) << 3)
#define RD(buf, row, ks) (*(const bhalf8*)&(buf)[(row) * 64 + SWZOFF(ks)])

#define PHASE_SYNC() do {                                        \
    __builtin_amdgcn_sched_barrier(0);                           \
    __builtin_amdgcn_s_barrier();                                \
    asm volatile("s_waitcnt lgkmcnt(0)" ::: "memory");           \
    __builtin_amdgcn_sched_barrier(0);                           \
} while (0)
#define PHASE_END() do {                                         \
    __builtin_amdgcn_sched_barrier(0);                           \
    __builtin_amdgcn_s_barrier();                                \
    __builtin_amdgcn_sched_barrier(0);                           \
} while (0)

    f32x4 acc[8][4] = {};

    STAGE_A(0, 0); STAGE_A(0, 1);
    STAGE_B(0, 0); STAGE_B(0, 1);
    STAGE_B(1, 0); STAGE_B(1, 1);
    asm volatile("s_waitcnt vmcnt(4)" ::: "memory");
    __builtin_amdgcn_s_barrier();
    __builtin_amdgcn_sched_barrier(0);

    for (int t = 0; t < NT; ++t) {
        const u16* as = &As[t & 1][0];
        const u16* bs = &Bs[t & 1][0];
        bhalf8 aLo[4][2], aHi[4][2], b0[2][2], b1[2][2];

        #pragma unroll
        for (int i = 0; i < 4; ++i) {
            aLo[i][0] = RD(as, wm * 128 + i * 16 + rlo, 0);
            aLo[i][1] = RD(as, wm * 128 + i * 16 + rlo, 1);
        }
        #pragma unroll
        for (int j = 0; j < 2; ++j) {
            b0[j][0] = RD(bs, wn * 64 + j * 16 + rlo, 0);
            b0[j][1] = RD(bs, wn * 64 + j * 16 + rlo, 1);
        }
        if (t + 1 < NT) STAGE_A(t + 1, 0);
        PHASE_SYNC();
        __builtin_amdgcn_s_setprio(1);
        #pragma unroll
        for (int i = 0; i < 4; ++i)
            #pragma unroll
            for (int j = 0; j < 2; ++j)
                #pragma unroll
                for (int ks = 0; ks < 2; ++ks)
                    acc[i][j] = __builtin_amdgcn_mfma_f32_16x16x32_bf16(b0[j][ks], aLo[i][ks], acc[i][j], 0, 0, 0);
        __builtin_amdgcn_s_setprio(0);
        PHASE_END();

        #pragma unroll
        for (int j = 0; j < 2; ++j) {
            b1[j][0] = RD(bs, wn * 64 + 32 + j * 16 + rlo, 0);
            b1[j][1] = RD(bs, wn * 64 + 32 + j * 16 + rlo, 1);
        }
        if (t + 1 < NT) STAGE_A(t + 1, 1);
        PHASE_SYNC();
        __builtin_amdgcn_s_setprio(1);
        #pragma unroll
        for (int i = 0; i < 4; ++i)
            #pragma unroll
            for (int j = 0; j < 2; ++j)
                #pragma unroll
                for (int ks = 0; ks < 2; ++ks)
                    acc[i][2 + j] = __builtin_amdgcn_mfma_f32_16x16x32_bf16(b1[j][ks], aLo[i][ks], acc[i][2 + j], 0, 0, 0);
        __builtin_amdgcn_s_setprio(0);
        PHASE_END();

        #pragma unroll
        for (int i = 0; i < 4; ++i) {
            aHi[i][0] = RD(as, wm * 128 + 64 + i * 16 + rlo, 0);
            aHi[i][1] = RD(as, wm * 128 + 64 + i * 16 + rlo, 1);
        }
        if (t + 2 < NT) STAGE_B(t + 2, 0);
        PHASE_SYNC();
        __builtin_amdgcn_s_setprio(1);
        #pragma unroll
        for (int i = 0; i < 4; ++i)
            #pragma unroll
            for (int j = 0; j < 2; ++j)
                #pragma unroll
                for (int ks = 0; ks < 2; ++ks)
                    acc[4 + i][j] = __builtin_amdgcn_mfma_f32_16x16x32_bf16(b0[j][ks], aHi[i][ks], acc[4 + i][j], 0, 0, 0);
        __builtin_amdgcn_s_setprio(0);
        PHASE_END();

        if (t + 2 < NT) {
            STAGE_B(t + 2, 1);
            asm volatile("s_waitcnt vmcnt(4)" ::: "memory");
        } else if (t < NT - 1) {
            asm volatile("s_waitcnt vmcnt(0)" ::: "memory");
        }
        PHASE_SYNC();
        __builtin_amdgcn_s_setprio(1);
        #pragma unroll
        for (int i = 0; i < 4; ++i)
            #pragma unroll
            for (int j = 0; j < 2; ++j)
                #pragma unroll
                for (int ks = 0; ks < 2; ++ks)
                    acc[4 + i][2 + j] = __builtin_amdgcn_mfma_f32_16x16x32_bf16(b1[j][ks], aHi[i][ks], acc[4 + i][2 + j], 0, 0, 0);
        __builtin_amdgcn_s_setprio(0);
        if (t < NT - 1) PHASE_END();
    }
#undef STAGE_A
#undef STAGE_B
#undef SWZOFF
#undef RD
#undef PHASE_SYNC
#undef PHASE_END

    const int row0 = m0 + wm * 128;
    const int col0 = n0 + wn * 64;
    const int rq   = (lane >> 4) * 4;
    float4 bi[4];
    #pragma unroll
    for (int j = 0; j < 4; ++j)
        bi[j] = *(const float4*)(bias + col0 + j * 16 + rq);

    #pragma unroll
    for (int i = 0; i < 8; ++i) {
        const int gr = row0 + i * 16 + rlo;
        u16* yrow = Y + (size_t)gr * N + col0;
        #pragma unroll
        for (int j = 0; j < 4; ++j) {
            float v0 = acc[i][j][0] + bi[j].x;
            float v1 = acc[i][j][1] + bi[j].y;
            float v2 = acc[i][j][2] + bi[j].z;
            float v3 = acc[i][j][3] + bi[j].w;
            if constexpr (GELU) {
                v0 = gelu_fast(v0); v1 = gelu_fast(v1);
                v2 = gelu_fast(v2); v3 = gelu_fast(v3);
            }
            ushort4 ov;
            ov.x = f2bf_hw(v0); ov.y = f2bf_hw(v1);
            ov.z = f2bf_hw(v2); ov.w = f2bf_hw(v3);
            *(ushort4*)(yrow + j * 16 + rq) = ov;
        }
    }
}

// ---------------------------------------------------------------------------
// Wbig builder: 2048x256 bf16.
// rows 0..511 = W_node[:,0:256]; 512..1023 = (Wq@W_node)[:,0:256];
// 1024..1535 = W_node[:,256:512]; 1536..2047 = (Wq@W_node)[:,256:512]
// ---------------------------------------------------------------------------
__global__ __launch_bounds__(256)
void build_wbig(const float* __restrict__ Wn, const float* __restrict__ Wq,
                u16* __restrict__ out)
{
    const int idx = blockIdx.x * 256 + threadIdx.x;   // 524288
    const int R = idx >> 8;
    const int k = idx & 255;
    float v;
    if (R < 512) {
        v = Wn[R * 512 + k];
    } else if (R < 1024) {
        const int c = R - 512; float a = 0.f;
        for (int j = 0; j < 512; j++) a += Wq[c * 512 + j] * Wn[j * 512 + k];
        v = a;
    } else if (R < 1536) {
        v = Wn[(R - 1024) * 512 + 256 + k];
    } else {
        const int c = R - 1536; float a = 0.f;
        for (int j = 0; j < 512; j++) a += Wq[c * 512 + j] * Wn[j * 512 + 256 + k];
        v = a;
    }
    out[idx] = f2bf(v);
}

// ---------------------------------------------------------------------------
// Wkt builder: 1024x256 bf16 (cols 128..255 zero padding), block-diag of
// wtk = Wk@W_timef: rows 0..511: [wtk[:,0:64] | 0...] ; 512..1023: [0 | wtk[:,64:128] | 0pad]
// ---------------------------------------------------------------------------
__global__ __launch_bounds__(256)
void build_wkt(const float* __restrict__ Wk, const float* __restrict__ Wtf,
               u16* __restrict__ out)
{
    const int idx = blockIdx.x * 256 + threadIdx.x;   // 262144
    const int R = idx >> 8;
    const int k = idx & 255;
    float v = 0.f;
    const bool live = (k < 128) && ((R < 512) ? (k < 64) : (k >= 64));
    if (live) {
        const int c = (R < 512) ? R : R - 512;
        float a = 0.f;
        for (int j = 0; j < 512; j++) a += Wk[c * 512 + j] * Wtf[j * 128 + k];
        v = a;
    }
    out[idx] = f2bf(v);
}

// ---------------------------------------------------------------------------
// TE: per-node time encoding, 256 cols (first 128 = dup sin enc, rest zero).
// ---------------------------------------------------------------------------
__global__ __launch_bounds__(256)
void te_kernel(const float* __restrict__ ts, const float* __restrict__ wtemb,
               const float* __restrict__ btemb, u16* __restrict__ TE)
{
    const int idx4 = (blockIdx.x * 256 + threadIdx.x) * 4;   // over 8192*256
    const int n = idx4 >> 8;
    const int j = idx4 & 255;
    ushort4 ov;
    if (j < 128) {
        const int kb = j & 63;
        const float tt = ts[n];
        ov.x = f2bf(sinf(tt * wtemb[kb + 0] + btemb[kb + 0]));
        ov.y = f2bf(sinf(tt * wtemb[kb + 1] + btemb[kb + 1]));
        ov.z = f2bf(sinf(tt * wtemb[kb + 2] + btemb[kb + 2]));
        ov.w = f2bf(sinf(tt * wtemb[kb + 3] + btemb[kb + 3]));
    } else {
        ov.x = ov.y = ov.z = ov.w = 0;
    }
    *(ushort4*)(TE + idx4) = ov;
}

// ---------------------------------------------------------------------------
// prep_e: edge-attr gather/convert into chunk rows (r = 4*el+b), 256 cols
// (128 data + 128 zero pad). 8 rows per 256-thr block, 32 lanes x 8 cols.
// ---------------------------------------------------------------------------
__global__ __launch_bounds__(256)
void prep_e(const float* __restrict__ eattr, u16* __restrict__ Ae, int e0)
{
    const int t  = threadIdx.x;
    const int r  = blockIdx.x * 8 + (t >> 5);
    const int cl = (t & 31) * 8;
    const int el = r >> 2;
    const int b  = r & 3;
    const int ge = e0 + el;
    uint4 ov;
    if (ge < EE && cl < 128) {
        const float* src = eattr + ((size_t)b * EE + ge) * 128 + cl;
        const float4 a = *(const float4*)src;
        const float4 c = *(const float4*)(src + 4);
        ov.x = (u32)f2bf(a.x) | ((u32)f2bf(a.y) << 16);
        ov.y = (u32)f2bf(a.z) | ((u32)f2bf(a.w) << 16);
        ov.z = (u32)f2bf(c.x) | ((u32)f2bf(c.y) << 16);
        ov.w = (u32)f2bf(c.z) | ((u32)f2bf(c.w) << 16);
    } else {
        ov.x = ov.y = ov.z = ov.w = 0;
    }
    *(uint4*)(Ae + (size_t)r * 256 + cl) = ov;
}

// ---------------------------------------------------------------------------
// helpers
// ---------------------------------------------------------------------------
__global__ __launch_bounds__(256)
void comb_w_bf(const float* __restrict__ Wa, const float* __restrict__ Wb,
               u16* __restrict__ out, int Kin, int ostride)
{
    const int idx  = blockIdx.x * 256 + threadIdx.x;
    const int c    = idx / Kin;
    const int kcol = idx - c * Kin;
    float acc = 0.f;
    for (int j = 0; j < CC; j++)
        acc += Wa[c * CC + j] * Wb[j * Kin + kcol];
    out[(size_t)c * ostride + kcol] = f2bf(acc);
}

__global__ __launch_bounds__(256)
void comb_b(const float* __restrict__ Wa, const float* __restrict__ bin,
            const float* __restrict__ ba, float* __restrict__ bout)
{
    const int c = blockIdx.x * 256 + threadIdx.x;
    float acc = ba[c];
    for (int j = 0; j < CC; j++)
        acc += Wa[c * CC + j] * bin[j];
    bout[c] = acc;
}

__global__ __launch_bounds__(256)
void cvt_bf(const float* __restrict__ in, u16* __restrict__ out, int n)
{
    const int i = (blockIdx.x * 256 + threadIdx.x) * 4;
    if (i < n) {
        const float4 v = *(const float4*)(in + i);
        ushort4 ov;
        ov.x = f2bf(v.x); ov.y = f2bf(v.y); ov.z = f2bf(v.z); ov.w = f2bf(v.w);
        *(ushort4*)(out + i) = ov;
    }
}

__global__ __launch_bounds__(256)
void zero_u16(u16* __restrict__ p, int n)
{
    const int i = blockIdx.x * 256 + threadIdx.x;
    if (i < n) p[i] = 0;
}

__global__ __launch_bounds__(256)
void copy_f32(const float* __restrict__ in, float* __restrict__ out, int n)
{
    const int i = blockIdx.x * 256 + threadIdx.x;
    if (i < n) out[i] = in[i];
}

// ---------------------------------------------------------------------------
// attn_fused: batch-axis attention with q/k gathered from per-node tables.
// q[r] = P[s][512:1024] + P[t][1536:2048] ; k[r] = KLR[s][0:512]+KLR[t][512:];
// v from kvv. Block = 4 edges x 64 lanes; ctx -> An.
// ---------------------------------------------------------------------------
__global__ __launch_bounds__(256)
void attn_fused(const u16* __restrict__ P, const u16* __restrict__ KLR,
                const u16* __restrict__ kvv, const int* __restrict__ ei,
                u16* __restrict__ ctx, int e0)
{
    const int el   = blockIdx.x * 4 + (threadIdx.x >> 6);
    const int ge   = e0 + el;
    const int lane = threadIdx.x & 63;
    const int off  = (lane >> 3) * 64 + (lane & 7) * 8;

    float qf[4][8], kf[4][8], vf[4][8];
    #pragma unroll
    for (int l = 0; l < 4; l++) {
        int s, t;
        if (ge < EE) {
            s = ei[(l * 2 + 0) * EE + ge];
            t = ei[(l * 2 + 1) * EE + ge];
        } else {
            s = t = ge - EE;
        }
        const size_t ns = (size_t)(l * NN + s);
        const size_t nt = (size_t)(l * NN + t);
        const uint4 qs = *(const uint4*)(P + ns * 2048 + 512 + off);
        const uint4 qt = *(const uint4*)(P + nt * 2048 + 1536 + off);
        const uint4 ks = *(const uint4*)(KLR + ns * 1024 + off);
        const uint4 kt = *(const uint4*)(KLR + nt * 1024 + 512 + off);
        const uint4 vx = *(const uint4*)(kvv + (size_t)(4 * el + l) * 512 + off);
        const u32 qa[4] = {qs.x, qs.y, qs.z, qs.w};
        const u32 qb[4] = {qt.x, qt.y, qt.z, qt.w};
        const u32 ka[4] = {ks.x, ks.y, ks.z, ks.w};
        const u32 kb[4] = {kt.x, kt.y, kt.z, kt.w};
        const u32 va[4] = {vx.x, vx.y, vx.z, vx.w};
        #pragma unroll
        for (int p = 0; p < 4; p++) {
            qf[l][2*p]   = bf2f((u16)qa[p])         + bf2f((u16)qb[p]);
            qf[l][2*p+1] = bf2f((u16)(qa[p] >> 16)) + bf2f((u16)(qb[p] >> 16));
            kf[l][2*p]   = bf2f((u16)ka[p])         + bf2f((u16)kb[p]);
            kf[l][2*p+1] = bf2f((u16)(ka[p] >> 16)) + bf2f((u16)(kb[p] >> 16));
            vf[l][2*p]   = bf2f((u16)va[p]);
            vf[l][2*p+1] = bf2f((u16)(va[p] >> 16));
        }
    }

    float sc[4][4];
    #pragma unroll
    for (int l = 0; l < 4; l++) {
        #pragma unroll
        for (int m = 0; m < 4; m++) {
            float p = 0.f;
            #pragma unroll
            for (int d = 0; d < 8; d++) p += qf[l][d] * kf[m][d];
            p += __shfl_xor(p, 1, 64);
            p += __shfl_xor(p, 2, 64);
            p += __shfl_xor(p, 4, 64);
            sc[l][m] = p * 0.125f;
        }
    }

    #pragma unroll
    for (int l = 0; l < 4; l++) {
        const float mx = fmaxf(fmaxf(sc[l][0], sc[l][1]), fmaxf(sc[l][2], sc[l][3]));
        float a[4], s = 0.f;
        #pragma unroll
        for (int m = 0; m < 4; m++) { a[m] = __expf(sc[l][m] - mx); s += a[m]; }
        const float inv = 1.0f / s;
        float cv[8];
        #pragma unroll
        for (int d = 0; d < 8; d++) {
            cv[d] = (a[0] * vf[0][d] + a[1] * vf[1][d] +
                     a[2] * vf[2][d] + a[3] * vf[3][d]) * inv;
        }
        ushort4 o0, o1;
        o0.x = f2bf(cv[0]); o0.y = f2bf(cv[1]); o0.z = f2bf(cv[2]); o0.w = f2bf(cv[3]);
        o1.x = f2bf(cv[4]); o1.y = f2bf(cv[5]); o1.z = f2bf(cv[6]); o1.w = f2bf(cv[7]);
        u16* crow = ctx + (size_t)(4 * el + l) * 512 + off;
        *(ushort4*)crow       = o0;
        *(ushort4*)(crow + 4) = o1;
    }
}

// ---------------------------------------------------------------------------
// ln1_fused (wave-per-row): out1 = LN(nodef + attn_out) -> bf16,
// nodef[r] = P[s][0:512] + P[t][1024:1536] gathered on the fly.
// ---------------------------------------------------------------------------
__global__ __launch_bounds__(256)
void ln1_fused(const u16* __restrict__ P, const u16* __restrict__ aout,
               const int* __restrict__ ei,
               const float* __restrict__ g, const float* __restrict__ be,
               u16* __restrict__ outb, int e0)
{
    const int r    = blockIdx.x * 4 + (threadIdx.x >> 6);
    const int lane = threadIdx.x & 63;
    const int c    = lane * 8;
    const int el   = r >> 2;
    const int b    = r & 3;
    const int ge   = e0 + el;

    int s, t;
    if (ge < EE) {
        s = ei[(b * 2 + 0) * EE + ge];
        t = ei[(b * 2 + 1) * EE + ge];
    } else {
        s = t = ge - EE;
    }

    const uint4 nfs = *(const uint4*)(P + (size_t)(b * NN + s) * 2048 + c);
    const uint4 nft = *(const uint4*)(P + (size_t)(b * NN + t) * 2048 + 1024 + c);
    const uint4 ao  = *(const uint4*)(aout + (size_t)r * 512 + c);
    const u32 na[4] = {nfs.x, nfs.y, nfs.z, nfs.w};
    const u32 nb[4] = {nft.x, nft.y, nft.z, nft.w};
    const u32 aa[4] = {ao.x, ao.y, ao.z, ao.w};

    float v[8];
    #pragma unroll
    for (int p = 0; p < 4; p++) {
        v[2*p]   = bf2f((u16)na[p])         + bf2f((u16)nb[p])         + bf2f((u16)aa[p]);
        v[2*p+1] = bf2f((u16)(na[p] >> 16)) + bf2f((u16)(nb[p] >> 16)) + bf2f((u16)(aa[p] >> 16));
    }

    float sum = 0.f;
    #pragma unroll
    for (int p = 0; p < 8; p++) sum += v[p];
    #pragma unroll
    for (int o = 32; o; o >>= 1) sum += __shfl_xor(sum, o, 64);
    const float mean = sum * (1.0f / 512.0f);

    float d[8], vs = 0.f;
    #pragma unroll
    for (int p = 0; p < 8; p++) { d[p] = v[p] - mean; vs += d[p] * d[p]; }
    #pragma unroll
    for (int o = 32; o; o >>= 1) vs += __shfl_xor(vs, o, 64);
    const float rstd = rsqrtf(vs * (1.0f / 512.0f) + 1e-5f);

    const float4 g0 = *(const float4*)(g + c),  g1 = *(const float4*)(g + c + 4);
    const float4 b0 = *(const float4*)(be + c), b1 = *(const float4*)(be + c + 4);
    const float gg[8] = {g0.x, g0.y, g0.z, g0.w, g1.x, g1.y, g1.z, g1.w};
    const float bb[8] = {b0.x, b0.y, b0.z, b0.w, b1.x, b1.y, b1.z, b1.w};

    uint4 ov;
    u32 w[4];
    #pragma unroll
    for (int p = 0; p < 4; p++) {
        const float y0 = d[2*p]   * rstd * gg[2*p]   + bb[2*p];
        const float y1 = d[2*p+1] * rstd * gg[2*p+1] + bb[2*p+1];
        w[p] = (u32)f2bf(y0) | ((u32)f2bf(y1) << 16);
    }
    ov.x = w[0]; ov.y = w[1]; ov.z = w[2]; ov.w = w[3];
    *(uint4*)(outb + (size_t)r * 512 + c) = ov;
}

// ---------------------------------------------------------------------------
// ln2 (wave-per-row): d_out[grow] = LN(out1 + ffn), f32 out.
// ---------------------------------------------------------------------------
__global__ __launch_bounds__(256)
void ln2_kernel(const u16* __restrict__ out1, const u16* __restrict__ ffn,
                const float* __restrict__ g, const float* __restrict__ be,
                float* __restrict__ out, int e0)
{
    const int r    = blockIdx.x * 4 + (threadIdx.x >> 6);
    const int lane = threadIdx.x & 63;
    const int c    = lane * 8;

    const uint4 o1 = *(const uint4*)(out1 + (size_t)r * 512 + c);
    const uint4 ff = *(const uint4*)(ffn  + (size_t)r * 512 + c);
    const u32 oa[4] = {o1.x, o1.y, o1.z, o1.w};
    const u32 fa[4] = {ff.x, ff.y, ff.z, ff.w};

    float v[8];
    #pragma unroll
    for (int p = 0; p < 4; p++) {
        v[2*p]   = bf2f((u16)oa[p])         + bf2f((u16)fa[p]);
        v[2*p+1] = bf2f((u16)(oa[p] >> 16)) + bf2f((u16)(fa[p] >> 16));
    }

    float s = 0.f;
    #pragma unroll
    for (int p = 0; p < 8; p++) s += v[p];
    #pragma unroll
    for (int o = 32; o; o >>= 1) s += __shfl_xor(s, o, 64);
    const float mean = s * (1.0f / 512.0f);

    float d[8], vs = 0.f;
    #pragma unroll
    for (int p = 0; p < 8; p++) { d[p] = v[p] - mean; vs += d[p] * d[p]; }
    #pragma unroll
    for (int o = 32; o; o >>= 1) vs += __shfl_xor(vs, o, 64);
    const float rstd = rsqrtf(vs * (1.0f / 512.0f) + 1e-5f);

    const float4 g0 = *(const float4*)(g + c),  g1 = *(const float4*)(g + c + 4);
    const float4 b0 = *(const float4*)(be + c), b1 = *(const float4*)(be + c + 4);

    const int el = r >> 2;
    const int b  = r & 3;
    float* orow = out + ((size_t)b * LL + e0 + el) * CC + c;
    float4 y0, y1;
    y0.x = d[0] * rstd * g0.x + b0.x;
    y0.y = d[1] * rstd * g0.y + b0.y;
    y0.z = d[2] * rstd * g0.z + b0.z;
    y0.w = d[3] * rstd * g0.w + b0.w;
    y1.x = d[4] * rstd * g1.x + b1.x;
    y1.y = d[5] * rstd * g1.y + b1.y;
    y1.z = d[6] * rstd * g1.z + b1.z;
    y1.w = d[7] * rstd * g1.w + b1.w;
    *(float4*)(orow)     = y0;
    *(float4*)(orow + 4) = y1;
}

// ---------------------------------------------------------------------------
extern "C" void kernel_launch(void* const* d_in, const int* in_sizes, int n_in,
                              void* d_out, int out_size, void* d_ws, size_t ws_size,
                              hipStream_t stream)
{
    const float* x       = (const float*)d_in[0];
    const float* eattr   = (const float*)d_in[1];
    const float* ts      = (const float*)d_in[2];
    const float* W_node  = (const float*)d_in[3];
    const float* b_node  = (const float*)d_in[4];
    const float* W_temb  = (const float*)d_in[5];
    const float* b_temb  = (const float*)d_in[6];
    const float* W_timef = (const float*)d_in[7];
    const float* b_timef = (const float*)d_in[8];
    const float* W_edge  = (const float*)d_in[9];
    const float* b_edge  = (const float*)d_in[10];
    const float* Wq      = (const float*)d_in[11];
    const float* bq      = (const float*)d_in[12];
    const float* Wk      = (const float*)d_in[13];
    const float* bk      = (const float*)d_in[14];
    const float* Wv      = (const float*)d_in[15];
    const float* bv      = (const float*)d_in[16];
    const float* Wo      = (const float*)d_in[17];
    const float* bo      = (const float*)d_in[18];
    const float* W1      = (const float*)d_in[19];
    const float* b1      = (const float*)d_in[20];
    const float* W2      = (const float*)d_in[21];
    const float* b2      = (const float*)d_in[22];
    const float* g1      = (const float*)d_in[23];
    const float* be1     = (const float*)d_in[24];
    const float* g2      = (const float*)d_in[25];
    const float* be2     = (const float*)d_in[26];
    const int*   ei      = (const int*)d_in[27];

    float* out = (float*)d_out;

    // ---- fixed region (u16 units) ----
    u16* wbig = (u16*)d_ws;                 // 2048x256  = 524288
    u16* wkt  = wbig + 524288;              // 1024x256  = 262144 (zero-padded)
    u16* wev  = wkt + 262144;               // 512x256   = 131072 (zero-padded)
    u16* wo   = wev + 131072;               // 512x512   = 262144
    u16* w1b  = wo + 262144;                // 2048x512  = 1048576
    u16* w2b  = w1b + 1048576;              // 512x2048  = 1048576
    u16* xb   = w2b + 1048576;              // 8192x256  = 2097152
    u16* TE   = xb + 2097152;               // 8192x256  = 2097152 (zero-padded)
    u16* P    = TE + 2097152;               // 8192x2048 = 16777216
    u16* KLR  = P + 16777216;               // 8192x1024 = 8388608
    float* bias2048 = (float*)(KLR + 8388608);  // 2048
    float* biasKLR  = bias2048 + 2048;          // 1024
    float* bev      = biasKLR + 1024;           // 512
    char*  cbase    = (char*)(bev + 512);
    const size_t fixedB = (size_t)(cbase - (char*)d_ws);

    // ---- chunk sizing: per edge = 4 rows x (256+512*3+2048) u16 = 30720 B --
    const size_t availB = (ws_size > fixedB) ? (ws_size - fixedB) : 0;
    int Ec = (int)(availB / 30720);
    Ec = (Ec / 64) * 64;                    // rows multiple of 256
    if (Ec > LL) Ec = LL;
    if (Ec < 64) Ec = 64;

    const size_t rmax = (size_t)4 * Ec;
    u16* Ae   = (u16*)cbase;                // rows x 256 (dedicated, no overlay)
    u16* kvv  = Ae + rmax * 256;            // rows x 512 (v)
    u16* An   = kvv + rmax * 512;           // rows x 512 (ctx -> out1)
    u16* aout = An + rmax * 512;            // rows x 512 (attn_out -> ffn)
    u16* hid  = aout + rmax * 512;          // rows x 2048

    const dim3 blk(256);
    const dim3 gblk(512);

    // ---- global precompute ----
    cvt_bf    <<<dim3(2048), blk, 0, stream>>>(x, xb, 2097152);
    build_wbig<<<dim3(2048), blk, 0, stream>>>(W_node, Wq, wbig);
    copy_f32  <<<dim3(2),    blk, 0, stream>>>(b_node, bias2048, 512);
    comb_b    <<<dim3(2),    blk, 0, stream>>>(Wq, b_node, bq, bias2048 + 512);
    zero_u16  <<<dim3(8),    blk, 0, stream>>>((u16*)(bias2048 + 1024), 2048);
    gemm_mfma<false><<<dim3(8, 32), gblk, 0, stream>>>(xb, wbig, bias2048, P, 2048, 256);

    te_kernel <<<dim3(2048), blk, 0, stream>>>(ts, W_temb, b_temb, TE);
    build_wkt <<<dim3(1024), blk, 0, stream>>>(Wk, W_timef, wkt);
    comb_b    <<<dim3(2),    blk, 0, stream>>>(Wk, b_timef, bk, biasKLR);
    zero_u16  <<<dim3(4),    blk, 0, stream>>>((u16*)(biasKLR + 512), 1024);
    gemm_mfma<false><<<dim3(4, 32), gblk, 0, stream>>>(TE, wkt, biasKLR, KLR, 1024, 256);

    zero_u16  <<<dim3(512),  blk, 0, stream>>>(wev, 131072);
    comb_w_bf <<<dim3(256),  blk, 0, stream>>>(Wv, W_edge, wev, 128, 256);
    comb_b    <<<dim3(2),    blk, 0, stream>>>(Wv, b_edge, bv, bev);
    cvt_bf    <<<dim3(256),  blk, 0, stream>>>(Wo, wo,  262144);
    cvt_bf    <<<dim3(1024), blk, 0, stream>>>(W1, w1b, 1048576);
    cvt_bf    <<<dim3(1024), blk, 0, stream>>>(W2, w2b, 1048576);

    for (int e0 = 0; e0 < LL; e0 += Ec) {
        int ec = LL - e0; if (ec > Ec) ec = Ec;
        const int rows = 4 * ec;
        const int gy = rows / 256;

        prep_e<<<dim3(rows / 8), blk, 0, stream>>>(eattr, Ae, e0);

        // v = Ae @ wev^T + bev   (K padded to 256, NT=4)
        gemm_mfma<false><<<dim3(2, gy), gblk, 0, stream>>>(Ae, wev, bev, kvv, 512, 256);

        // attention with gathered q/k ; ctx -> An
        attn_fused<<<dim3(ec / 4), blk, 0, stream>>>(P, KLR, kvv, ei, An, e0);

        // attn_out = ctx @ Wo^T + bo ; out1 = LN(gathered nodef + attn_out)
        gemm_mfma<false><<<dim3(2, gy), gblk, 0, stream>>>(An, wo, bo, aout, 512, 512);
        ln1_fused<<<dim3(rows / 4), blk, 0, stream>>>(P, aout, ei, g1, be1, An, e0);

        // FFN
        gemm_mfma<true ><<<dim3(8, gy), gblk, 0, stream>>>(An,  w1b, b1, hid, 2048, 512);
        gemm_mfma<false><<<dim3(2, gy), gblk, 0, stream>>>(hid, w2b, b2, aout, 512, 2048);

        ln2_kernel<<<dim3(rows / 4), blk, 0, stream>>>(An, aout, g2, be2, out, e0);
    }
}